// Round 6
// baseline (1509.549 us; speedup 1.0000x reference)
//
#include <hip/hip_runtime.h>
#include <cstdint>
#include <cstddef>

// ---------------------------------------------------------------------------
// TopoGNN: 3x SAGEConv(mean) + BN + ReLU, softmax-attention pooling, 2 heads.
// N=100000 nodes, E=1600000 edges, B=64 segments, IN_CH=6, HID=64.
// R1: scatter atomics -> CSR pull. R2: multi-block scan, 2-node matmul.
// R3: bucket partition (cheap) but LDS-tile agg FAILED in R4 (occupancy).
// R5: packed bucket partition + per-bucket local CSR; 754us; pool_kernel top
//     (115us @ 2.6% occupancy -- 64 blocks on 256 CUs).
// R6: fusion round. bn_stats fused into matmul producers (LDS reduce +
//     global atomics); bn_relu applied on-the-fly in consumers (h stays raw);
//     pool replaced by high-parallelism bn_pool (wave-per-chunk, register
//     accumulate, atomic flush on segment change only).
// ---------------------------------------------------------------------------

#define EPB 8192   // edges per partition block (256 thr x 32)
#define NBIN 512   // padded bucket count (actual NB = ceil(N/256) <= 512)
#define EPS_BN 1e-5f

// ---- phase A: per-block bucket histogram ---------------------------------
__global__ __launch_bounds__(256) void bucket_hist(const int* __restrict__ dst,
                                                   int* __restrict__ blockBin,
                                                   int* __restrict__ binTotal, int E)
{
    __shared__ int hist[NBIN];
    int t = threadIdx.x;
    for (int i = t; i < NBIN; i += 256) hist[i] = 0;
    __syncthreads();
    int e0 = blockIdx.x * EPB;
#pragma unroll
    for (int k = 0; k < 32; k++) {
        int e = e0 + (k << 8) + t;
        if (e < E) atomicAdd(&hist[dst[e] >> 8], 1);
    }
    __syncthreads();
    for (int i = t; i < NBIN; i += 256) {
        int c = hist[i];
        blockBin[blockIdx.x * NBIN + i] = c;
        if (c) atomicAdd(&binTotal[i], c);
    }
}

// ---- phase B: scan bin totals -> binBase; blockBin counts -> abs offsets
__global__ __launch_bounds__(512) void bin_scan(const int* __restrict__ binTotal,
                                                int* __restrict__ binBase,
                                                int* __restrict__ blockBin,
                                                int* __restrict__ rowptrN, int nBlk)
{
    __shared__ int s[NBIN];
    int t = threadIdx.x;
    int tot = binTotal[t];
    s[t] = tot;
    __syncthreads();
    for (int off = 1; off < NBIN; off <<= 1) {
        int v = (t >= off) ? s[t - off] : 0;
        __syncthreads();
        s[t] += v;
        __syncthreads();
    }
    int excl = s[t] - tot;
    binBase[t] = excl;
    if (t == NBIN - 1) { binBase[NBIN] = s[t]; *rowptrN = s[t]; }
    int run = excl;
    for (int blk = 0; blk < nBlk; blk++) {
        int idx = blk * NBIN + t;
        int c = blockBin[idx];
        blockBin[idx] = run;
        run += c;
    }
}

// ---- phase C: place packed (src | local_dst<<24); per-block LDS cursors ---
__global__ __launch_bounds__(256) void bucket_scatter(const int* __restrict__ src,
                                                      const int* __restrict__ dst,
                                                      const int* __restrict__ blockBin,
                                                      int* __restrict__ epck, int E)
{
    __shared__ int cur[NBIN];
    int t = threadIdx.x;
    for (int i = t; i < NBIN; i += 256) cur[i] = blockBin[blockIdx.x * NBIN + i];
    __syncthreads();
    int e0 = blockIdx.x * EPB;
#pragma unroll
    for (int k = 0; k < 32; k++) {
        int e = e0 + (k << 8) + t;
        if (e < E) {
            int d = dst[e];
            int pos = atomicAdd(&cur[d >> 8], 1);
            epck[pos] = src[e] | ((d & 255) << 24);   // src < 2^24
        }
    }
}

// ---- phase D: per-bucket local CSR --------------------------------------
__global__ __launch_bounds__(256) void csr_local(const int* __restrict__ epck,
                                                 const int* __restrict__ binBase,
                                                 int* __restrict__ rowptr,
                                                 int* __restrict__ eidx, int N)
{
    __shared__ int cnt[256], s[256], cur[256];
    int t = threadIdx.x, bkt = blockIdx.x;
    int base = binBase[bkt], nE = binBase[bkt + 1] - base;
    cnt[t] = 0;
    __syncthreads();
    for (int j = t; j < nE; j += 256)
        atomicAdd(&cnt[(unsigned)epck[base + j] >> 24], 1);
    __syncthreads();
    s[t] = cnt[t];
    __syncthreads();
    for (int off = 1; off < 256; off <<= 1) {
        int v = (t >= off) ? s[t - off] : 0;
        __syncthreads();
        s[t] += v;
        __syncthreads();
    }
    int excl = s[t] - cnt[t];
    cur[t] = excl;
    int node = (bkt << 8) + t;
    if (node < N) rowptr[node] = base + excl;
    __syncthreads();
    for (int j = t; j < nE; j += 256) {
        int v = epck[base + j];
        int pos = atomicAdd(&cur[(unsigned)v >> 24], 1);
        eidx[base + pos] = v & 0xFFFFFF;     // contiguous 16KB span: stays in L2
    }
}

// ---- layer 1: pull-agg (6ch) + matmul + fused BN stats --------------------
__global__ __launch_bounds__(256) void sage1_fused(
    const int* __restrict__ rowptr, const int* __restrict__ eidx,
    const float* __restrict__ x,
    const float* __restrict__ Wl, const float* __restrict__ bias,
    const float* __restrict__ Wr,
    float* __restrict__ out, float* __restrict__ statsOut, int n)
{
    __shared__ float4 sWl[6 * 16];
    __shared__ float4 sWr[6 * 16];
    __shared__ float  ls[64], lss[64];
    int t = threadIdx.x;
    if (t < 96) { sWl[t] = ((const float4*)Wl)[t]; sWr[t] = ((const float4*)Wr)[t]; }
    if (t < 64) { ls[t] = 0.f; lss[t] = 0.f; }
    __syncthreads();

    int node = blockIdx.x * 256 + t;
    if (node < n) {
        int b = rowptr[node], e = rowptr[node + 1];
        float a[6] = {0.f, 0.f, 0.f, 0.f, 0.f, 0.f};
        for (int j = b; j < e; j++) {
            int s = eidx[j];
            const float2* r = (const float2*)(x + (size_t)s * 6);
            float2 r0 = r[0], r1 = r[1], r2 = r[2];
            a[0] += r0.x; a[1] += r0.y; a[2] += r1.x;
            a[3] += r1.y; a[4] += r2.x; a[5] += r2.y;
        }
        float invd = 1.0f / fmaxf((float)(e - b), 1.0f);

        const float2* xr2 = (const float2*)(x + (size_t)node * 6);
        float2 x0 = xr2[0], x1 = xr2[1], x2 = xr2[2];
        float hh[6] = {x0.x, x0.y, x1.x, x1.y, x2.x, x2.y};

        float4 acc[16];
#pragma unroll
        for (int cg = 0; cg < 16; cg++) acc[cg] = ((const float4*)bias)[cg];
#pragma unroll
        for (int k = 0; k < 6; k++) {
            float am = a[k] * invd;
            float hk = hh[k];
#pragma unroll
            for (int cg = 0; cg < 16; cg++) {
                float4 wl = sWl[k * 16 + cg];
                float4 wr = sWr[k * 16 + cg];
                acc[cg].x = fmaf(am, wl.x, fmaf(hk, wr.x, acc[cg].x));
                acc[cg].y = fmaf(am, wl.y, fmaf(hk, wr.y, acc[cg].y));
                acc[cg].z = fmaf(am, wl.z, fmaf(hk, wr.z, acc[cg].z));
                acc[cg].w = fmaf(am, wl.w, fmaf(hk, wr.w, acc[cg].w));
            }
        }
        float4* orow = (float4*)(out + (size_t)node * 64);
#pragma unroll
        for (int cg = 0; cg < 16; cg++) {
            orow[cg] = acc[cg];
            int c = cg * 4;
            atomicAdd(&ls[c + 0], acc[cg].x); atomicAdd(&lss[c + 0], acc[cg].x * acc[cg].x);
            atomicAdd(&ls[c + 1], acc[cg].y); atomicAdd(&lss[c + 1], acc[cg].y * acc[cg].y);
            atomicAdd(&ls[c + 2], acc[cg].z); atomicAdd(&lss[c + 2], acc[cg].z * acc[cg].z);
            atomicAdd(&ls[c + 3], acc[cg].w); atomicAdd(&lss[c + 3], acc[cg].w * acc[cg].w);
        }
    }
    __syncthreads();
    if (t < 64) {
        unsafeAtomicAdd(&statsOut[t], ls[t]);
        unsafeAtomicAdd(&statsOut[64 + t], lss[t]);
    }
}

// ---- pull aggregation with on-the-fly BN+ReLU of the gathered rows --------
__global__ __launch_bounds__(256) void aggpull64_bn(
    const int* __restrict__ rowptr, const int* __restrict__ eidx,
    const float* __restrict__ h, const float* __restrict__ stats,
    const float* __restrict__ g, const float* __restrict__ be,
    float* __restrict__ agg, float invN, int n)
{
    int w    = (blockIdx.x * 256 + threadIdx.x) >> 6;
    int lane = threadIdx.x & 63;
    if (w >= n) return;
    float mu  = stats[lane] * invN;
    float var = stats[64 + lane] * invN - mu * mu;
    float sc  = g[lane] / sqrtf(var + EPS_BN);
    float sh  = fmaf(-mu, sc, be[lane]);

    int b = rowptr[w], e = rowptr[w + 1];
    float acc0 = 0.f, acc1 = 0.f, acc2 = 0.f, acc3 = 0.f;
    for (int j0 = b; j0 < e; j0 += 64) {
        int myidx = (j0 + lane < e) ? eidx[j0 + lane] : 0;
        int m = min(64, e - j0);
        int jj = 0;
        for (; jj + 4 <= m; jj += 4) {
            int s0 = __shfl(myidx, jj,     64);
            int s1 = __shfl(myidx, jj + 1, 64);
            int s2 = __shfl(myidx, jj + 2, 64);
            int s3 = __shfl(myidx, jj + 3, 64);
            acc0 += fmaxf(fmaf(h[(size_t)s0 * 64 + lane], sc, sh), 0.f);
            acc1 += fmaxf(fmaf(h[(size_t)s1 * 64 + lane], sc, sh), 0.f);
            acc2 += fmaxf(fmaf(h[(size_t)s2 * 64 + lane], sc, sh), 0.f);
            acc3 += fmaxf(fmaf(h[(size_t)s3 * 64 + lane], sc, sh), 0.f);
        }
        for (; jj < m; jj++) {
            int s = __shfl(myidx, jj, 64);
            acc0 += fmaxf(fmaf(h[(size_t)s * 64 + lane], sc, sh), 0.f);
        }
    }
    agg[(size_t)w * 64 + lane] = acc0 + acc1 + acc2 + acc3;
}

// ---- 64x64 matmul: agg (pre-normalized sums) + on-the-fly-BN self term,
//      2 nodes/thread, fused output BN stats --------------------------------
__global__ __launch_bounds__(256) void sage_matmul64(
    const float* __restrict__ agg, const float* __restrict__ hraw,
    const int* __restrict__ rowptr,
    const float* __restrict__ statsIn, const float* __restrict__ gIn,
    const float* __restrict__ beIn,
    const float* __restrict__ Wl, const float* __restrict__ bias,
    const float* __restrict__ Wr,
    float* __restrict__ out, float* __restrict__ statsOut, float invN, int n)
{
    __shared__ float4 sWl[64 * 16];
    __shared__ float4 sWr[64 * 16];
    __shared__ float  ssc[64], ssh[64], ls[64], lss[64];
    int t = threadIdx.x;
    for (int i = t; i < 64 * 16; i += 256) {
        sWl[i] = ((const float4*)Wl)[i];
        sWr[i] = ((const float4*)Wr)[i];
    }
    if (t < 64) {
        float mu  = statsIn[t] * invN;
        float var = statsIn[64 + t] * invN - mu * mu;
        float sc  = gIn[t] / sqrtf(var + EPS_BN);
        ssc[t] = sc;
        ssh[t] = fmaf(-mu, sc, beIn[t]);
        ls[t] = 0.f; lss[t] = 0.f;
    }
    __syncthreads();

    int node0 = blockIdx.x * 512 + t;
    if (node0 < n) {
        int  node1 = node0 + 256;
        bool has1  = (node1 < n);
        int  n1    = has1 ? node1 : node0;

        float invd0 = 1.0f / fmaxf((float)(rowptr[node0 + 1] - rowptr[node0]), 1.0f);
        float invd1 = 1.0f / fmaxf((float)(rowptr[n1 + 1] - rowptr[n1]), 1.0f);

        float4 acc0[16], acc1[16];
#pragma unroll
        for (int cg = 0; cg < 16; cg++) {
            float4 bv = ((const float4*)bias)[cg];
            acc0[cg] = bv;
            acc1[cg] = bv;
        }

        const float4* ar0 = (const float4*)(agg  + (size_t)node0 * 64);
        const float4* hr0 = (const float4*)(hraw + (size_t)node0 * 64);
        const float4* ar1 = (const float4*)(agg  + (size_t)n1 * 64);
        const float4* hr1 = (const float4*)(hraw + (size_t)n1 * 64);

#pragma unroll 1   // body fits L1I; inner j/cg fully unrolled
        for (int k4 = 0; k4 < 16; k4++) {
            float4 a0 = ar0[k4], h0 = hr0[k4];
            float4 a1 = ar1[k4], h1 = hr1[k4];
            float aa0[4] = {a0.x, a0.y, a0.z, a0.w}, hh0[4] = {h0.x, h0.y, h0.z, h0.w};
            float aa1[4] = {a1.x, a1.y, a1.z, a1.w}, hh1[4] = {h1.x, h1.y, h1.z, h1.w};
#pragma unroll
            for (int j = 0; j < 4; j++) {
                int k = k4 * 4 + j;
                float sck = ssc[k], shk = ssh[k];
                float am0 = aa0[j] * invd0;
                float am1 = aa1[j] * invd1;
                float hk0 = fmaxf(fmaf(hh0[j], sck, shk), 0.f);
                float hk1 = fmaxf(fmaf(hh1[j], sck, shk), 0.f);
#pragma unroll
                for (int cg = 0; cg < 16; cg++) {
                    float4 wl = sWl[k * 16 + cg];
                    float4 wr = sWr[k * 16 + cg];
                    acc0[cg].x = fmaf(am0, wl.x, fmaf(hk0, wr.x, acc0[cg].x));
                    acc0[cg].y = fmaf(am0, wl.y, fmaf(hk0, wr.y, acc0[cg].y));
                    acc0[cg].z = fmaf(am0, wl.z, fmaf(hk0, wr.z, acc0[cg].z));
                    acc0[cg].w = fmaf(am0, wl.w, fmaf(hk0, wr.w, acc0[cg].w));
                    acc1[cg].x = fmaf(am1, wl.x, fmaf(hk1, wr.x, acc1[cg].x));
                    acc1[cg].y = fmaf(am1, wl.y, fmaf(hk1, wr.y, acc1[cg].y));
                    acc1[cg].z = fmaf(am1, wl.z, fmaf(hk1, wr.z, acc1[cg].z));
                    acc1[cg].w = fmaf(am1, wl.w, fmaf(hk1, wr.w, acc1[cg].w));
                }
            }
        }
        float4* o0 = (float4*)(out + (size_t)node0 * 64);
#pragma unroll
        for (int cg = 0; cg < 16; cg++) o0[cg] = acc0[cg];
        if (has1) {
            float4* o1 = (float4*)(out + (size_t)node1 * 64);
#pragma unroll
            for (int cg = 0; cg < 16; cg++) o1[cg] = acc1[cg];
        }
        // fused BN stats on raw outputs
        float w1 = has1 ? 1.0f : 0.0f;
#pragma unroll
        for (int cg = 0; cg < 16; cg++) {
            int c = cg * 4;
            float vx0 = acc0[cg].x, vx1 = acc1[cg].x * w1;
            float vy0 = acc0[cg].y, vy1 = acc1[cg].y * w1;
            float vz0 = acc0[cg].z, vz1 = acc1[cg].z * w1;
            float vw0 = acc0[cg].w, vw1 = acc1[cg].w * w1;
            atomicAdd(&ls[c + 0], vx0 + vx1); atomicAdd(&lss[c + 0], vx0 * vx0 + vx1 * vx1);
            atomicAdd(&ls[c + 1], vy0 + vy1); atomicAdd(&lss[c + 1], vy0 * vy0 + vy1 * vy1);
            atomicAdd(&ls[c + 2], vz0 + vz1); atomicAdd(&lss[c + 2], vz0 * vz0 + vz1 * vz1);
            atomicAdd(&ls[c + 3], vw0 + vw1); atomicAdd(&lss[c + 3], vw0 * vw0 + vw1 * vw1);
        }
    }
    __syncthreads();
    if (t < 64) {
        unsafeAtomicAdd(&statsOut[t], ls[t]);
        unsafeAtomicAdd(&statsOut[64 + t], lss[t]);
    }
}

// ---- fused layer-3 BN+ReLU + attention-weighted segment pooling -----------
// wave per ~chunk contiguous nodes; lane = channel; flush on segment change.
__global__ __launch_bounds__(256) void bn_pool(
    const float* __restrict__ h, const float* __restrict__ stats,
    const float* __restrict__ g, const float* __restrict__ be,
    const float* __restrict__ x, const int* __restrict__ batch,
    float* __restrict__ rawpool, float invN, int N, int chunk)
{
    int wid  = blockIdx.x * 4 + (threadIdx.x >> 6);
    int lane = threadIdx.x & 63;
    int i0 = wid * chunk;
    if (i0 >= N) return;
    int i1 = min(i0 + chunk, N);

    float mu  = stats[lane] * invN;
    float var = stats[64 + lane] * invN - mu * mu;
    float sc  = g[lane] / sqrtf(var + EPS_BN);
    float sh  = fmaf(-mu, sc, be[lane]);

    int   cur = batch[i0];
    float acc = 0.f;
    for (int i = i0; i < i1; i++) {
        int bi = batch[i];
        if (bi != cur) {
            unsafeAtomicAdd(&rawpool[cur * 64 + lane], acc);
            acc = 0.f;
            cur = bi;
        }
        float w = expf(x[(size_t)i * 6 + 4]);
        float v = fmaxf(fmaf(h[(size_t)i * 64 + lane], sc, sh), 0.f);
        acc = fmaf(v, w, acc);
    }
    unsafeAtomicAdd(&rawpool[cur * 64 + lane], acc);
}

// ---- softmax denominator (shift-invariant: min-sub + 1e-8 drop out) -------
__global__ __launch_bounds__(256) void softmax_sum(const float* __restrict__ x,
                                                   float* __restrict__ sumexp, int n)
{
    float s = 0.f;
    int stride = gridDim.x * 256;
    for (int i = blockIdx.x * 256 + threadIdx.x; i < n; i += stride)
        s += expf(x[(size_t)i * 6 + 4]);
#pragma unroll
    for (int o = 32; o > 0; o >>= 1) s += __shfl_down(s, o, 64);
    __shared__ float wsum[4];
    if ((threadIdx.x & 63) == 0) wsum[threadIdx.x >> 6] = s;
    __syncthreads();
    if (threadIdx.x == 0)
        unsafeAtomicAdd(sumexp, wsum[0] + wsum[1] + wsum[2] + wsum[3]);
}

__global__ void seg_bounds(const int* __restrict__ batch, int* __restrict__ lb, int n)
{
    int b = threadIdx.x;
    if (b > 64) return;
    int lo = 0, hi = n;
    while (lo < hi) {
        int mid = (lo + hi) >> 1;
        if (batch[mid] < b) lo = mid + 1; else hi = mid;
    }
    lb[b] = lo;
}

// ---- heads: normalize rawpool by 1/sumexp and counts, then 2 tiny MLPs ----
__global__ __launch_bounds__(64) void heads_kernel(
    const float* __restrict__ rawpool, const float* __restrict__ sumexp,
    const int* __restrict__ lb,
    const float* __restrict__ phW1, const float* __restrict__ phb1,
    const float* __restrict__ phW2, const float* __restrict__ phb2,
    const float* __restrict__ trW1, const float* __restrict__ trb1,
    const float* __restrict__ trW2, const float* __restrict__ trb2,
    float* __restrict__ out)
{
    int b = blockIdx.x, t = threadIdx.x;
    __shared__ float p[64], h1[32], h2[16];
    float cnt = (float)(lb[b + 1] - lb[b]);
    p[t] = rawpool[b * 64 + t] / (sumexp[0] * fmaxf(cnt, 1.0f));
    __syncthreads();
    if (t < 32) {
        float s = phb1[t];
        for (int k = 0; k < 64; k++) s = fmaf(p[k], phW1[k * 32 + t], s);
        h1[t] = fmaxf(s, 0.f);
    } else if (t < 48) {
        int tt = t - 32;
        float s = trb1[tt];
        for (int k = 0; k < 64; k++) s = fmaf(p[k], trW1[k * 16 + tt], s);
        h2[tt] = fmaxf(s, 0.f);
    }
    __syncthreads();
    if (t < 3) {
        float s = phb2[t];
        for (int k = 0; k < 32; k++) s = fmaf(h1[k], phW2[k * 3 + t], s);
        out[b * 3 + t] = s;
    } else if (t == 63) {
        float s = trb2[0];
        for (int k = 0; k < 16; k++) s = fmaf(h2[k], trW2[k], s);
        out[192 + b] = 1.0f / (1.0f + expf(-s));
    }
}

extern "C" void kernel_launch(void* const* d_in, const int* in_sizes, int n_in,
                              void* d_out, int out_size, void* d_ws, size_t ws_size,
                              hipStream_t stream)
{
    const float* x     = (const float*)d_in[0];
    const int*   ei    = (const int*)d_in[1];
    const int*   batch = (const int*)d_in[2];
    const float* W1l = (const float*)d_in[3];
    const float* b1  = (const float*)d_in[4];
    const float* W1r = (const float*)d_in[5];
    const float* W2l = (const float*)d_in[6];
    const float* b2  = (const float*)d_in[7];
    const float* W2r = (const float*)d_in[8];
    const float* W3l = (const float*)d_in[9];
    const float* b3  = (const float*)d_in[10];
    const float* W3r = (const float*)d_in[11];
    const float* g1  = (const float*)d_in[12];
    const float* be1 = (const float*)d_in[13];
    const float* g2  = (const float*)d_in[14];
    const float* be2 = (const float*)d_in[15];
    const float* g3  = (const float*)d_in[16];
    const float* be3 = (const float*)d_in[17];
    const float* phW1 = (const float*)d_in[18];
    const float* phb1 = (const float*)d_in[19];
    const float* phW2 = (const float*)d_in[20];
    const float* phb2 = (const float*)d_in[21];
    const float* trW1 = (const float*)d_in[22];
    const float* trb1 = (const float*)d_in[23];
    const float* trW2 = (const float*)d_in[24];
    const float* trb2 = (const float*)d_in[25];

    const int N = in_sizes[0] / 6;
    const int E = in_sizes[1] / 2;
    const int* src = ei;
    const int* dst = ei + E;

    const int NB    = (N + 255) >> 8;          // 391 buckets
    const int nBlkA = (E + EPB - 1) / EPB;     // 196 partition blocks

    float* ws = (float*)d_ws;
    const size_t N64 = (size_t)N * 64;
    float* agg      = ws;                          // N*64
    float* hA       = ws + N64;                    // N*64 (h1 raw, then h3 raw)
    float* hB       = ws + 2 * N64;                // N*64 (h2 raw)
    int*   epck     = (int*)(ws + 3 * N64);        // E packed src|dl<<24
    int*   eidx     = epck + E;                    // E (CSR by dst)
    int*   blockBin = eidx + E;                    // nBlkA * NBIN
    // --- contiguous zero region: binTotal + stats[3][128] + rawpool + sumexp
    int*   binTotal = blockBin + (size_t)nBlkA * NBIN;   // NBIN
    float* stats    = (float*)(binTotal + NBIN);   // 3 * 128
    float* rawpool  = stats + 384;                 // 64*64
    float* sumexp   = rawpool + 4096;              // 1 (pad 4)
    // --- end zero region ---
    int*   binBase  = (int*)(sumexp + 4);          // NBIN + 1
    int*   rowptr   = binBase + NBIN + 1;          // N + 1
    int*   lb       = rowptr + N + 1;              // 65 (pad 72)
    float* out      = (float*)d_out;

    const int nodeBlocks = (N + 255) / 256;
    const int waveNodeBlocks = (int)(((size_t)N * 64 + 255) / 256);
    const int mm2Blocks = (N + 511) / 512;
    const int PBLK = 1024;                         // bn_pool blocks (4 waves each)
    const int chunk = (N + PBLK * 4 - 1) / (PBLK * 4);
    const float invN = 1.0f / (float)N;

    // ---- zero accumulators; independent softmax reduction first ----
    size_t zbytes = (char*)(sumexp + 4) - (char*)binTotal;
    hipMemsetAsync(binTotal, 0, zbytes, stream);
    softmax_sum<<<256, 256, 0, stream>>>(x, sumexp, N);
    seg_bounds<<<1, 128, 0, stream>>>(batch, lb, N);

    // ---- CSR build via bucket partition ----
    bucket_hist<<<nBlkA, 256, 0, stream>>>(dst, blockBin, binTotal, E);
    bin_scan<<<1, NBIN, 0, stream>>>(binTotal, binBase, blockBin, rowptr + N, nBlkA);
    bucket_scatter<<<nBlkA, 256, 0, stream>>>(src, dst, blockBin, epck, E);
    csr_local<<<NB, 256, 0, stream>>>(epck, binBase, rowptr, eidx, N);

    // ---- layer 1: agg6+matmul -> hA raw, stats1 ----
    sage1_fused<<<nodeBlocks, 256, 0, stream>>>(rowptr, eidx, x, W1l, b1, W1r,
                                                hA, stats, N);
    // ---- layer 2: BN1 on the fly ----
    aggpull64_bn<<<waveNodeBlocks, 256, 0, stream>>>(rowptr, eidx, hA, stats,
                                                     g1, be1, agg, invN, N);
    sage_matmul64<<<mm2Blocks, 256, 0, stream>>>(agg, hA, rowptr, stats, g1, be1,
                                                 W2l, b2, W2r, hB, stats + 128,
                                                 invN, N);
    // ---- layer 3: BN2 on the fly ----
    aggpull64_bn<<<waveNodeBlocks, 256, 0, stream>>>(rowptr, eidx, hB, stats + 128,
                                                     g2, be2, agg, invN, N);
    sage_matmul64<<<mm2Blocks, 256, 0, stream>>>(agg, hB, rowptr, stats + 128, g2, be2,
                                                 W3l, b3, W3r, hA, stats + 256,
                                                 invN, N);
    // ---- fused BN3 + attention pooling + heads ----
    bn_pool<<<PBLK, 256, 0, stream>>>(hA, stats + 256, g3, be3, x, batch,
                                      rawpool, invN, N, chunk);
    heads_kernel<<<64, 64, 0, stream>>>(rawpool, sumexp, lb,
                                        phW1, phb1, phW2, phb2,
                                        trW1, trb1, trW2, trb2, out);
}

// Round 7
// 643.750 us; speedup vs baseline: 2.3449x; 2.3449x over previous
//
#include <hip/hip_runtime.h>
#include <cstdint>
#include <cstddef>

// ---------------------------------------------------------------------------
// TopoGNN: 3x SAGEConv(mean) + BN + ReLU, softmax-attention pooling, 2 heads.
// N=100000 nodes, E=1600000 edges, B=64 segments, IN_CH=6, HID=64.
// R5 (754us): packed bucket partition + per-bucket local CSR + register pull.
// R6 FAILED (1510us): fusing BN stats into matmul kernels spilled to scratch
//     (VGPR 256, 172MB spill writes in sage1_fused). bn_pool itself was fine.
// R7: R5 compute kernels restored verbatim; keep ONLY bn_pool (fused layer-3
//     BN+ReLU+attention-pool, 4096 waves) replacing bn_relu3+pool_kernel
//     (115us @ 2.6% occupancy).
// ---------------------------------------------------------------------------

#define EPB 8192   // edges per partition block (256 thr x 32)
#define NBIN 512   // padded bucket count (actual NB = ceil(N/256) <= 512)
#define EPS_BN 1e-5f

// ---- phase A: per-block bucket histogram ---------------------------------
__global__ __launch_bounds__(256) void bucket_hist(const int* __restrict__ dst,
                                                   int* __restrict__ blockBin,
                                                   int* __restrict__ binTotal, int E)
{
    __shared__ int hist[NBIN];
    int t = threadIdx.x;
    for (int i = t; i < NBIN; i += 256) hist[i] = 0;
    __syncthreads();
    int e0 = blockIdx.x * EPB;
#pragma unroll
    for (int k = 0; k < 32; k++) {
        int e = e0 + (k << 8) + t;
        if (e < E) atomicAdd(&hist[dst[e] >> 8], 1);
    }
    __syncthreads();
    for (int i = t; i < NBIN; i += 256) {
        int c = hist[i];
        blockBin[blockIdx.x * NBIN + i] = c;
        if (c) atomicAdd(&binTotal[i], c);
    }
}

// ---- phase B: scan bin totals -> binBase; blockBin counts -> abs offsets
__global__ __launch_bounds__(512) void bin_scan(const int* __restrict__ binTotal,
                                                int* __restrict__ binBase,
                                                int* __restrict__ blockBin,
                                                int* __restrict__ rowptrN, int nBlk)
{
    __shared__ int s[NBIN];
    int t = threadIdx.x;
    int tot = binTotal[t];
    s[t] = tot;
    __syncthreads();
    for (int off = 1; off < NBIN; off <<= 1) {
        int v = (t >= off) ? s[t - off] : 0;
        __syncthreads();
        s[t] += v;
        __syncthreads();
    }
    int excl = s[t] - tot;
    binBase[t] = excl;
    if (t == NBIN - 1) { binBase[NBIN] = s[t]; *rowptrN = s[t]; }
    int run = excl;
    for (int blk = 0; blk < nBlk; blk++) {
        int idx = blk * NBIN + t;
        int c = blockBin[idx];
        blockBin[idx] = run;
        run += c;
    }
}

// ---- phase C: place packed (src | local_dst<<24); per-block LDS cursors ---
__global__ __launch_bounds__(256) void bucket_scatter(const int* __restrict__ src,
                                                      const int* __restrict__ dst,
                                                      const int* __restrict__ blockBin,
                                                      int* __restrict__ epck, int E)
{
    __shared__ int cur[NBIN];
    int t = threadIdx.x;
    for (int i = t; i < NBIN; i += 256) cur[i] = blockBin[blockIdx.x * NBIN + i];
    __syncthreads();
    int e0 = blockIdx.x * EPB;
#pragma unroll
    for (int k = 0; k < 32; k++) {
        int e = e0 + (k << 8) + t;
        if (e < E) {
            int d = dst[e];
            int pos = atomicAdd(&cur[d >> 8], 1);
            epck[pos] = src[e] | ((d & 255) << 24);   // src < 2^24
        }
    }
}

// ---- phase D: per-bucket local CSR --------------------------------------
__global__ __launch_bounds__(256) void csr_local(const int* __restrict__ epck,
                                                 const int* __restrict__ binBase,
                                                 int* __restrict__ rowptr,
                                                 int* __restrict__ eidx, int N)
{
    __shared__ int cnt[256], s[256], cur[256];
    int t = threadIdx.x, bkt = blockIdx.x;
    int base = binBase[bkt], nE = binBase[bkt + 1] - base;
    cnt[t] = 0;
    __syncthreads();
    for (int j = t; j < nE; j += 256)
        atomicAdd(&cnt[(unsigned)epck[base + j] >> 24], 1);
    __syncthreads();
    s[t] = cnt[t];
    __syncthreads();
    for (int off = 1; off < 256; off <<= 1) {
        int v = (t >= off) ? s[t - off] : 0;
        __syncthreads();
        s[t] += v;
        __syncthreads();
    }
    int excl = s[t] - cnt[t];
    cur[t] = excl;
    int node = (bkt << 8) + t;
    if (node < N) rowptr[node] = base + excl;
    __syncthreads();
    for (int j = t; j < nE; j += 256) {
        int v = epck[base + j];
        int pos = atomicAdd(&cur[(unsigned)v >> 24], 1);
        eidx[base + pos] = v & 0xFFFFFF;     // contiguous 16KB span: stays in L2
    }
}

// ---- layer 1: fused pull-aggregation (6 ch) + matmul (R5 verbatim) --------
__global__ __launch_bounds__(256) void sage1_fused(
    const int* __restrict__ rowptr, const int* __restrict__ eidx,
    const float* __restrict__ x,
    const float* __restrict__ Wl, const float* __restrict__ bias,
    const float* __restrict__ Wr, float* __restrict__ out, int n)
{
    __shared__ float4 sWl[6 * 16];
    __shared__ float4 sWr[6 * 16];
    for (int i = threadIdx.x; i < 6 * 16; i += 256) {
        sWl[i] = ((const float4*)Wl)[i];
        sWr[i] = ((const float4*)Wr)[i];
    }
    __syncthreads();

    int node = blockIdx.x * 256 + threadIdx.x;
    if (node >= n) return;

    int b = rowptr[node], e = rowptr[node + 1];
    float a[6] = {0.f, 0.f, 0.f, 0.f, 0.f, 0.f};
    for (int j = b; j < e; j++) {
        int s = eidx[j];
        const float2* r = (const float2*)(x + (size_t)s * 6);
        float2 r0 = r[0], r1 = r[1], r2 = r[2];
        a[0] += r0.x; a[1] += r0.y; a[2] += r1.x;
        a[3] += r1.y; a[4] += r2.x; a[5] += r2.y;
    }
    float invd = 1.0f / fmaxf((float)(e - b), 1.0f);

    const float2* xr2 = (const float2*)(x + (size_t)node * 6);
    float2 x0 = xr2[0], x1 = xr2[1], x2 = xr2[2];
    float hh[6] = {x0.x, x0.y, x1.x, x1.y, x2.x, x2.y};

    float4 acc[16];
#pragma unroll
    for (int cg = 0; cg < 16; cg++) acc[cg] = ((const float4*)bias)[cg];
#pragma unroll
    for (int k = 0; k < 6; k++) {
        float am = a[k] * invd;
        float hk = hh[k];
#pragma unroll
        for (int cg = 0; cg < 16; cg++) {
            float4 wl = sWl[k * 16 + cg];
            float4 wr = sWr[k * 16 + cg];
            acc[cg].x = fmaf(am, wl.x, fmaf(hk, wr.x, acc[cg].x));
            acc[cg].y = fmaf(am, wl.y, fmaf(hk, wr.y, acc[cg].y));
            acc[cg].z = fmaf(am, wl.z, fmaf(hk, wr.z, acc[cg].z));
            acc[cg].w = fmaf(am, wl.w, fmaf(hk, wr.w, acc[cg].w));
        }
    }
    float4* orow = (float4*)(out + (size_t)node * 64);
#pragma unroll
    for (int cg = 0; cg < 16; cg++) orow[cg] = acc[cg];
}

// ---- 64-ch pull aggregation (R5 verbatim) ---------------------------------
__global__ __launch_bounds__(256) void aggpull64(const int* __restrict__ rowptr,
                                                 const int* __restrict__ eidx,
                                                 const float* __restrict__ h,
                                                 float* __restrict__ agg, int n)
{
    int w    = (blockIdx.x * 256 + threadIdx.x) >> 6;
    int lane = threadIdx.x & 63;
    if (w >= n) return;
    int b = rowptr[w], e = rowptr[w + 1];
    float acc0 = 0.f, acc1 = 0.f, acc2 = 0.f, acc3 = 0.f;
    for (int j0 = b; j0 < e; j0 += 64) {
        int myidx = (j0 + lane < e) ? eidx[j0 + lane] : 0;
        int m = min(64, e - j0);
        int jj = 0;
        for (; jj + 4 <= m; jj += 4) {
            int s0 = __shfl(myidx, jj,     64);
            int s1 = __shfl(myidx, jj + 1, 64);
            int s2 = __shfl(myidx, jj + 2, 64);
            int s3 = __shfl(myidx, jj + 3, 64);
            acc0 += h[(size_t)s0 * 64 + lane];
            acc1 += h[(size_t)s1 * 64 + lane];
            acc2 += h[(size_t)s2 * 64 + lane];
            acc3 += h[(size_t)s3 * 64 + lane];
        }
        for (; jj < m; jj++) {
            int s = __shfl(myidx, jj, 64);
            acc0 += h[(size_t)s * 64 + lane];
        }
    }
    agg[(size_t)w * 64 + lane] = acc0 + acc1 + acc2 + acc3;
}

// ---- 64x64 matmul, 2 nodes/thread (R5 verbatim) ---------------------------
__global__ __launch_bounds__(256) void sage_matmul64(
    const float* __restrict__ agg, const float* __restrict__ hin,
    const int* __restrict__ rowptr, const float* __restrict__ Wl,
    const float* __restrict__ bias, const float* __restrict__ Wr,
    float* __restrict__ out, int n)
{
    __shared__ float4 sWl[64 * 16];
    __shared__ float4 sWr[64 * 16];
    for (int i = threadIdx.x; i < 64 * 16; i += 256) {
        sWl[i] = ((const float4*)Wl)[i];
        sWr[i] = ((const float4*)Wr)[i];
    }
    __syncthreads();

    int node0 = blockIdx.x * 512 + threadIdx.x;
    if (node0 >= n) return;
    int  node1 = node0 + 256;
    bool has1  = (node1 < n);
    int  n1    = has1 ? node1 : node0;

    float invd0 = 1.0f / fmaxf((float)(rowptr[node0 + 1] - rowptr[node0]), 1.0f);
    float invd1 = 1.0f / fmaxf((float)(rowptr[n1 + 1] - rowptr[n1]), 1.0f);

    float4 acc0[16], acc1[16];
#pragma unroll
    for (int cg = 0; cg < 16; cg++) {
        float4 bv = ((const float4*)bias)[cg];
        acc0[cg] = bv;
        acc1[cg] = bv;
    }

    const float4* ar0 = (const float4*)(agg + (size_t)node0 * 64);
    const float4* hr0 = (const float4*)(hin + (size_t)node0 * 64);
    const float4* ar1 = (const float4*)(agg + (size_t)n1 * 64);
    const float4* hr1 = (const float4*)(hin + (size_t)n1 * 64);

#pragma unroll 1   // keep body ~10KB: fits L1I; inner j/cg fully unrolled
    for (int k4 = 0; k4 < 16; k4++) {
        float4 a0 = ar0[k4], h0 = hr0[k4];
        float4 a1 = ar1[k4], h1 = hr1[k4];
        float aa0[4] = {a0.x, a0.y, a0.z, a0.w}, hh0[4] = {h0.x, h0.y, h0.z, h0.w};
        float aa1[4] = {a1.x, a1.y, a1.z, a1.w}, hh1[4] = {h1.x, h1.y, h1.z, h1.w};
#pragma unroll
        for (int j = 0; j < 4; j++) {
            float am0 = aa0[j] * invd0, hk0 = hh0[j];
            float am1 = aa1[j] * invd1, hk1 = hh1[j];
            int k = k4 * 4 + j;
#pragma unroll
            for (int cg = 0; cg < 16; cg++) {
                float4 wl = sWl[k * 16 + cg];
                float4 wr = sWr[k * 16 + cg];
                acc0[cg].x = fmaf(am0, wl.x, fmaf(hk0, wr.x, acc0[cg].x));
                acc0[cg].y = fmaf(am0, wl.y, fmaf(hk0, wr.y, acc0[cg].y));
                acc0[cg].z = fmaf(am0, wl.z, fmaf(hk0, wr.z, acc0[cg].z));
                acc0[cg].w = fmaf(am0, wl.w, fmaf(hk0, wr.w, acc0[cg].w));
                acc1[cg].x = fmaf(am1, wl.x, fmaf(hk1, wr.x, acc1[cg].x));
                acc1[cg].y = fmaf(am1, wl.y, fmaf(hk1, wr.y, acc1[cg].y));
                acc1[cg].z = fmaf(am1, wl.z, fmaf(hk1, wr.z, acc1[cg].z));
                acc1[cg].w = fmaf(am1, wl.w, fmaf(hk1, wr.w, acc1[cg].w));
            }
        }
    }
    float4* o0 = (float4*)(out + (size_t)node0 * 64);
#pragma unroll
    for (int cg = 0; cg < 16; cg++) o0[cg] = acc0[cg];
    if (has1) {
        float4* o1 = (float4*)(out + (size_t)node1 * 64);
#pragma unroll
        for (int cg = 0; cg < 16; cg++) o1[cg] = acc1[cg];
    }
}

// ---- BatchNorm (separate passes — R5 verbatim) ----------------------------

__global__ __launch_bounds__(256) void bn_stats(const float* __restrict__ h,
                                                float* __restrict__ stats, size_t total)
{
    __shared__ float ls[64], lss[64];
    if (threadIdx.x < 64) { ls[threadIdx.x] = 0.f; lss[threadIdx.x] = 0.f; }
    __syncthreads();
    float s = 0.f, ss = 0.f;
    size_t stride = (size_t)gridDim.x * 256;
    for (size_t i = (size_t)blockIdx.x * 256 + threadIdx.x; i < total; i += stride) {
        float v = h[i];
        s += v;
        ss = fmaf(v, v, ss);
    }
    int c = threadIdx.x & 63;
    atomicAdd(&ls[c], s);
    atomicAdd(&lss[c], ss);
    __syncthreads();
    if (threadIdx.x < 64) {
        unsafeAtomicAdd(&stats[threadIdx.x], ls[threadIdx.x]);
        unsafeAtomicAdd(&stats[64 + threadIdx.x], lss[threadIdx.x]);
    }
}

__global__ __launch_bounds__(256) void bn_relu(float* __restrict__ h,
                                               const float* __restrict__ stats,
                                               const float* __restrict__ g,
                                               const float* __restrict__ be,
                                               float inv_n, size_t total)
{
    size_t i = (size_t)blockIdx.x * 256 + threadIdx.x;
    if (i >= total) return;
    int   c   = threadIdx.x & 63;
    float mu  = stats[c] * inv_n;
    float var = stats[64 + c] * inv_n - mu * mu;
    float sc  = g[c] / sqrtf(var + EPS_BN);
    float sh  = fmaf(-mu, sc, be[c]);
    h[i] = fmaxf(fmaf(h[i], sc, sh), 0.f);
}

// ---- fused layer-3 BN+ReLU + attention-weighted segment pooling -----------
// wave per ~chunk contiguous nodes; lane = channel; flush on segment change.
__global__ __launch_bounds__(256) void bn_pool(
    const float* __restrict__ h, const float* __restrict__ stats,
    const float* __restrict__ g, const float* __restrict__ be,
    const float* __restrict__ x, const int* __restrict__ batch,
    float* __restrict__ rawpool, float invN, int N, int chunk)
{
    int wid  = blockIdx.x * 4 + (threadIdx.x >> 6);
    int lane = threadIdx.x & 63;
    int i0 = wid * chunk;
    if (i0 >= N) return;
    int i1 = min(i0 + chunk, N);

    float mu  = stats[lane] * invN;
    float var = stats[64 + lane] * invN - mu * mu;
    float sc  = g[lane] / sqrtf(var + EPS_BN);
    float sh  = fmaf(-mu, sc, be[lane]);

    int   cur = batch[i0];
    float acc = 0.f;
    for (int i = i0; i < i1; i++) {
        int bi = batch[i];
        if (bi != cur) {
            unsafeAtomicAdd(&rawpool[cur * 64 + lane], acc);
            acc = 0.f;
            cur = bi;
        }
        float w = expf(x[(size_t)i * 6 + 4]);
        float v = fmaxf(fmaf(h[(size_t)i * 64 + lane], sc, sh), 0.f);
        acc = fmaf(v, w, acc);
    }
    unsafeAtomicAdd(&rawpool[cur * 64 + lane], acc);
}

// ---- softmax denominator (shift-invariant: min-sub + 1e-8 drop out) -------
__global__ __launch_bounds__(256) void softmax_sum(const float* __restrict__ x,
                                                   float* __restrict__ sumexp, int n)
{
    float s = 0.f;
    int stride = gridDim.x * 256;
    for (int i = blockIdx.x * 256 + threadIdx.x; i < n; i += stride)
        s += expf(x[(size_t)i * 6 + 4]);
#pragma unroll
    for (int o = 32; o > 0; o >>= 1) s += __shfl_down(s, o, 64);
    __shared__ float wsum[4];
    if ((threadIdx.x & 63) == 0) wsum[threadIdx.x >> 6] = s;
    __syncthreads();
    if (threadIdx.x == 0)
        unsafeAtomicAdd(sumexp, wsum[0] + wsum[1] + wsum[2] + wsum[3]);
}

__global__ void seg_bounds(const int* __restrict__ batch, int* __restrict__ lb, int n)
{
    int b = threadIdx.x;
    if (b > 64) return;
    int lo = 0, hi = n;
    while (lo < hi) {
        int mid = (lo + hi) >> 1;
        if (batch[mid] < b) lo = mid + 1; else hi = mid;
    }
    lb[b] = lo;
}

// ---- heads: normalize rawpool by 1/sumexp and counts, then 2 tiny MLPs ----
__global__ __launch_bounds__(64) void heads_kernel(
    const float* __restrict__ rawpool, const float* __restrict__ sumexp,
    const int* __restrict__ lb,
    const float* __restrict__ phW1, const float* __restrict__ phb1,
    const float* __restrict__ phW2, const float* __restrict__ phb2,
    const float* __restrict__ trW1, const float* __restrict__ trb1,
    const float* __restrict__ trW2, const float* __restrict__ trb2,
    float* __restrict__ out)
{
    int b = blockIdx.x, t = threadIdx.x;
    __shared__ float p[64], h1[32], h2[16];
    float cnt = (float)(lb[b + 1] - lb[b]);
    p[t] = rawpool[b * 64 + t] / (sumexp[0] * fmaxf(cnt, 1.0f));
    __syncthreads();
    if (t < 32) {
        float s = phb1[t];
        for (int k = 0; k < 64; k++) s = fmaf(p[k], phW1[k * 32 + t], s);
        h1[t] = fmaxf(s, 0.f);
    } else if (t < 48) {
        int tt = t - 32;
        float s = trb1[tt];
        for (int k = 0; k < 64; k++) s = fmaf(p[k], trW1[k * 16 + tt], s);
        h2[tt] = fmaxf(s, 0.f);
    }
    __syncthreads();
    if (t < 3) {
        float s = phb2[t];
        for (int k = 0; k < 32; k++) s = fmaf(h1[k], phW2[k * 3 + t], s);
        out[b * 3 + t] = s;
    } else if (t == 63) {
        float s = trb2[0];
        for (int k = 0; k < 16; k++) s = fmaf(h2[k], trW2[k], s);
        out[192 + b] = 1.0f / (1.0f + expf(-s));
    }
}

extern "C" void kernel_launch(void* const* d_in, const int* in_sizes, int n_in,
                              void* d_out, int out_size, void* d_ws, size_t ws_size,
                              hipStream_t stream)
{
    const float* x     = (const float*)d_in[0];
    const int*   ei    = (const int*)d_in[1];
    const int*   batch = (const int*)d_in[2];
    const float* W1l = (const float*)d_in[3];
    const float* b1  = (const float*)d_in[4];
    const float* W1r = (const float*)d_in[5];
    const float* W2l = (const float*)d_in[6];
    const float* b2  = (const float*)d_in[7];
    const float* W2r = (const float*)d_in[8];
    const float* W3l = (const float*)d_in[9];
    const float* b3  = (const float*)d_in[10];
    const float* W3r = (const float*)d_in[11];
    const float* g1  = (const float*)d_in[12];
    const float* be1 = (const float*)d_in[13];
    const float* g2  = (const float*)d_in[14];
    const float* be2 = (const float*)d_in[15];
    const float* g3  = (const float*)d_in[16];
    const float* be3 = (const float*)d_in[17];
    const float* phW1 = (const float*)d_in[18];
    const float* phb1 = (const float*)d_in[19];
    const float* phW2 = (const float*)d_in[20];
    const float* phb2 = (const float*)d_in[21];
    const float* trW1 = (const float*)d_in[22];
    const float* trb1 = (const float*)d_in[23];
    const float* trW2 = (const float*)d_in[24];
    const float* trb2 = (const float*)d_in[25];

    const int N = in_sizes[0] / 6;
    const int E = in_sizes[1] / 2;
    const int* src = ei;
    const int* dst = ei + E;

    const int NB    = (N + 255) >> 8;          // 391 buckets
    const int nBlkA = (E + EPB - 1) / EPB;     // 196 partition blocks

    float* ws = (float*)d_ws;
    const size_t N64 = (size_t)N * 64;
    float* agg      = ws;                          // N*64
    float* hA       = ws + N64;                    // N*64 (h1, then h3 raw)
    float* hB       = ws + 2 * N64;                // N*64 (h2)
    int*   epck     = (int*)(ws + 3 * N64);        // E packed src|dl<<24
    int*   eidx     = epck + E;                    // E (CSR by dst)
    int*   blockBin = eidx + E;                    // nBlkA * NBIN
    // --- contiguous zero region: binTotal + stats[3][128] + rawpool + sumexp
    int*   binTotal = blockBin + (size_t)nBlkA * NBIN;   // NBIN
    float* stats    = (float*)(binTotal + NBIN);   // 3 * 128
    float* rawpool  = stats + 384;                 // 64*64
    float* sumexp   = rawpool + 4096;              // 1 (pad 4)
    // --- end zero region ---
    int*   binBase  = (int*)(sumexp + 4);          // NBIN + 1
    int*   rowptr   = binBase + NBIN + 1;          // N + 1
    int*   lb       = rowptr + N + 1;              // 65 (pad 72)
    float* out      = (float*)d_out;

    const int nodeBlocks = (N + 255) / 256;
    const int waveNodeBlocks = (int)(((size_t)N * 64 + 255) / 256);
    const int ewBlocks  = (int)((N64 + 255) / 256);
    const int mm2Blocks = (N + 511) / 512;
    const int PBLK = 1024;                         // bn_pool blocks (4 waves each)
    const int chunk = (N + PBLK * 4 - 1) / (PBLK * 4);
    const float invN = 1.0f / (float)N;

    // ---- zero accumulators; independent reductions first ----
    size_t zbytes = (char*)(sumexp + 4) - (char*)binTotal;
    hipMemsetAsync(binTotal, 0, zbytes, stream);
    softmax_sum<<<256, 256, 0, stream>>>(x, sumexp, N);
    seg_bounds<<<1, 128, 0, stream>>>(batch, lb, N);

    // ---- CSR build via bucket partition ----
    bucket_hist<<<nBlkA, 256, 0, stream>>>(dst, blockBin, binTotal, E);
    bin_scan<<<1, NBIN, 0, stream>>>(binTotal, binBase, blockBin, rowptr + N, nBlkA);
    bucket_scatter<<<nBlkA, 256, 0, stream>>>(src, dst, blockBin, epck, E);
    csr_local<<<NB, 256, 0, stream>>>(epck, binBase, rowptr, eidx, N);

    // ---- layer 1 (6 ch, aggregation fused into matmul) ----
    sage1_fused<<<nodeBlocks, 256, 0, stream>>>(rowptr, eidx, x, W1l, b1, W1r, hA, N);
    bn_stats<<<1024, 256, 0, stream>>>(hA, stats, N64);
    bn_relu<<<ewBlocks, 256, 0, stream>>>(hA, stats, g1, be1, invN, N64);

    // ---- layer 2 ----
    aggpull64<<<waveNodeBlocks, 256, 0, stream>>>(rowptr, eidx, hA, agg, N);
    sage_matmul64<<<mm2Blocks, 256, 0, stream>>>(agg, hA, rowptr, W2l, b2, W2r, hB, N);
    bn_stats<<<1024, 256, 0, stream>>>(hB, stats + 128, N64);
    bn_relu<<<ewBlocks, 256, 0, stream>>>(hB, stats + 128, g2, be2, invN, N64);

    // ---- layer 3 ----
    aggpull64<<<waveNodeBlocks, 256, 0, stream>>>(rowptr, eidx, hB, agg, N);
    sage_matmul64<<<mm2Blocks, 256, 0, stream>>>(agg, hB, rowptr, W3l, b3, W3r, hA, N);
    bn_stats<<<1024, 256, 0, stream>>>(hA, stats + 256, N64);

    // ---- fused BN3 + attention pooling + heads ----
    bn_pool<<<PBLK, 256, 0, stream>>>(hA, stats + 256, g3, be3, x, batch,
                                      rawpool, invN, N, chunk);
    heads_kernel<<<64, 64, 0, stream>>>(rawpool, sumexp, lb,
                                        phW1, phb1, phW2, phb2,
                                        trW1, trb1, trW2, trb2, out);
}

// Round 8
// 593.249 us; speedup vs baseline: 2.5445x; 1.0851x over previous
//
#include <hip/hip_runtime.h>
#include <cstdint>
#include <cstddef>

// ---------------------------------------------------------------------------
// TopoGNN: 3x SAGEConv(mean) + BN + ReLU, softmax-attention pooling, 2 heads.
// N=100000 nodes, E=1600000 edges, B=64 segments, IN_CH=6, HID=64.
// R5 (754us): bucket partition + per-bucket local CSR + register pull.
// R6 FAILED: output-stats fusion spilled (VGPR 256). Input-side BN fusion and
//     bn_pool were fine.
// R7 (644us): R5 compute + bn_pool. Top: sage_matmul64 76us @ 7.4% occupancy
//     (grid 196 blocks < 256 CUs -- 2-node/thread halved the grid).
// R8: mm64_bn_split -- channel-split matmul (2 lanes/node, 128 nodes/block,
//     782 blocks, acc 8 float4) with fused input-side BN+ReLU self-term;
//     aggpull64_bn (R6) applies BN+ReLU to gathered neighbors. Both bn_relu
//     write-back passes eliminated. Output stats stay as separate bn_stats.
// ---------------------------------------------------------------------------

#define EPB 8192   // edges per partition block (256 thr x 32)
#define NBIN 512   // padded bucket count (actual NB = ceil(N/256) <= 512)
#define EPS_BN 1e-5f

// ---- phase A: per-block bucket histogram ---------------------------------
__global__ __launch_bounds__(256) void bucket_hist(const int* __restrict__ dst,
                                                   int* __restrict__ blockBin,
                                                   int* __restrict__ binTotal, int E)
{
    __shared__ int hist[NBIN];
    int t = threadIdx.x;
    for (int i = t; i < NBIN; i += 256) hist[i] = 0;
    __syncthreads();
    int e0 = blockIdx.x * EPB;
#pragma unroll
    for (int k = 0; k < 32; k++) {
        int e = e0 + (k << 8) + t;
        if (e < E) atomicAdd(&hist[dst[e] >> 8], 1);
    }
    __syncthreads();
    for (int i = t; i < NBIN; i += 256) {
        int c = hist[i];
        blockBin[blockIdx.x * NBIN + i] = c;
        if (c) atomicAdd(&binTotal[i], c);
    }
}

// ---- phase B: scan bin totals -> binBase; blockBin counts -> abs offsets
__global__ __launch_bounds__(512) void bin_scan(const int* __restrict__ binTotal,
                                                int* __restrict__ binBase,
                                                int* __restrict__ blockBin,
                                                int* __restrict__ rowptrN, int nBlk)
{
    __shared__ int s[NBIN];
    int t = threadIdx.x;
    int tot = binTotal[t];
    s[t] = tot;
    __syncthreads();
    for (int off = 1; off < NBIN; off <<= 1) {
        int v = (t >= off) ? s[t - off] : 0;
        __syncthreads();
        s[t] += v;
        __syncthreads();
    }
    int excl = s[t] - tot;
    binBase[t] = excl;
    if (t == NBIN - 1) { binBase[NBIN] = s[t]; *rowptrN = s[t]; }
    int run = excl;
    for (int blk = 0; blk < nBlk; blk++) {
        int idx = blk * NBIN + t;
        int c = blockBin[idx];
        blockBin[idx] = run;
        run += c;
    }
}

// ---- phase C: place packed (src | local_dst<<24); per-block LDS cursors ---
__global__ __launch_bounds__(256) void bucket_scatter(const int* __restrict__ src,
                                                      const int* __restrict__ dst,
                                                      const int* __restrict__ blockBin,
                                                      int* __restrict__ epck, int E)
{
    __shared__ int cur[NBIN];
    int t = threadIdx.x;
    for (int i = t; i < NBIN; i += 256) cur[i] = blockBin[blockIdx.x * NBIN + i];
    __syncthreads();
    int e0 = blockIdx.x * EPB;
#pragma unroll
    for (int k = 0; k < 32; k++) {
        int e = e0 + (k << 8) + t;
        if (e < E) {
            int d = dst[e];
            int pos = atomicAdd(&cur[d >> 8], 1);
            epck[pos] = src[e] | ((d & 255) << 24);   // src < 2^24
        }
    }
}

// ---- phase D: per-bucket local CSR --------------------------------------
__global__ __launch_bounds__(256) void csr_local(const int* __restrict__ epck,
                                                 const int* __restrict__ binBase,
                                                 int* __restrict__ rowptr,
                                                 int* __restrict__ eidx, int N)
{
    __shared__ int cnt[256], s[256], cur[256];
    int t = threadIdx.x, bkt = blockIdx.x;
    int base = binBase[bkt], nE = binBase[bkt + 1] - base;
    cnt[t] = 0;
    __syncthreads();
    for (int j = t; j < nE; j += 256)
        atomicAdd(&cnt[(unsigned)epck[base + j] >> 24], 1);
    __syncthreads();
    s[t] = cnt[t];
    __syncthreads();
    for (int off = 1; off < 256; off <<= 1) {
        int v = (t >= off) ? s[t - off] : 0;
        __syncthreads();
        s[t] += v;
        __syncthreads();
    }
    int excl = s[t] - cnt[t];
    cur[t] = excl;
    int node = (bkt << 8) + t;
    if (node < N) rowptr[node] = base + excl;
    __syncthreads();
    for (int j = t; j < nE; j += 256) {
        int v = epck[base + j];
        int pos = atomicAdd(&cur[(unsigned)v >> 24], 1);
        eidx[base + pos] = v & 0xFFFFFF;     // contiguous 16KB span: stays in L2
    }
}

// ---- layer 1: fused pull-aggregation (6 ch) + matmul (R5 verbatim) --------
__global__ __launch_bounds__(256) void sage1_fused(
    const int* __restrict__ rowptr, const int* __restrict__ eidx,
    const float* __restrict__ x,
    const float* __restrict__ Wl, const float* __restrict__ bias,
    const float* __restrict__ Wr, float* __restrict__ out, int n)
{
    __shared__ float4 sWl[6 * 16];
    __shared__ float4 sWr[6 * 16];
    for (int i = threadIdx.x; i < 6 * 16; i += 256) {
        sWl[i] = ((const float4*)Wl)[i];
        sWr[i] = ((const float4*)Wr)[i];
    }
    __syncthreads();

    int node = blockIdx.x * 256 + threadIdx.x;
    if (node >= n) return;

    int b = rowptr[node], e = rowptr[node + 1];
    float a[6] = {0.f, 0.f, 0.f, 0.f, 0.f, 0.f};
    for (int j = b; j < e; j++) {
        int s = eidx[j];
        const float2* r = (const float2*)(x + (size_t)s * 6);
        float2 r0 = r[0], r1 = r[1], r2 = r[2];
        a[0] += r0.x; a[1] += r0.y; a[2] += r1.x;
        a[3] += r1.y; a[4] += r2.x; a[5] += r2.y;
    }
    float invd = 1.0f / fmaxf((float)(e - b), 1.0f);

    const float2* xr2 = (const float2*)(x + (size_t)node * 6);
    float2 x0 = xr2[0], x1 = xr2[1], x2 = xr2[2];
    float hh[6] = {x0.x, x0.y, x1.x, x1.y, x2.x, x2.y};

    float4 acc[16];
#pragma unroll
    for (int cg = 0; cg < 16; cg++) acc[cg] = ((const float4*)bias)[cg];
#pragma unroll
    for (int k = 0; k < 6; k++) {
        float am = a[k] * invd;
        float hk = hh[k];
#pragma unroll
        for (int cg = 0; cg < 16; cg++) {
            float4 wl = sWl[k * 16 + cg];
            float4 wr = sWr[k * 16 + cg];
            acc[cg].x = fmaf(am, wl.x, fmaf(hk, wr.x, acc[cg].x));
            acc[cg].y = fmaf(am, wl.y, fmaf(hk, wr.y, acc[cg].y));
            acc[cg].z = fmaf(am, wl.z, fmaf(hk, wr.z, acc[cg].z));
            acc[cg].w = fmaf(am, wl.w, fmaf(hk, wr.w, acc[cg].w));
        }
    }
    float4* orow = (float4*)(out + (size_t)node * 64);
#pragma unroll
    for (int cg = 0; cg < 16; cg++) orow[cg] = acc[cg];
}

// ---- pull aggregation with on-the-fly BN+ReLU of gathered rows (R6) -------
__global__ __launch_bounds__(256) void aggpull64_bn(
    const int* __restrict__ rowptr, const int* __restrict__ eidx,
    const float* __restrict__ h, const float* __restrict__ stats,
    const float* __restrict__ g, const float* __restrict__ be,
    float* __restrict__ agg, float invN, int n)
{
    int w    = (blockIdx.x * 256 + threadIdx.x) >> 6;
    int lane = threadIdx.x & 63;
    if (w >= n) return;
    float mu  = stats[lane] * invN;
    float var = stats[64 + lane] * invN - mu * mu;
    float sc  = g[lane] / sqrtf(var + EPS_BN);
    float sh  = fmaf(-mu, sc, be[lane]);

    int b = rowptr[w], e = rowptr[w + 1];
    float acc0 = 0.f, acc1 = 0.f, acc2 = 0.f, acc3 = 0.f;
    for (int j0 = b; j0 < e; j0 += 64) {
        int myidx = (j0 + lane < e) ? eidx[j0 + lane] : 0;
        int m = min(64, e - j0);
        int jj = 0;
        for (; jj + 4 <= m; jj += 4) {
            int s0 = __shfl(myidx, jj,     64);
            int s1 = __shfl(myidx, jj + 1, 64);
            int s2 = __shfl(myidx, jj + 2, 64);
            int s3 = __shfl(myidx, jj + 3, 64);
            acc0 += fmaxf(fmaf(h[(size_t)s0 * 64 + lane], sc, sh), 0.f);
            acc1 += fmaxf(fmaf(h[(size_t)s1 * 64 + lane], sc, sh), 0.f);
            acc2 += fmaxf(fmaf(h[(size_t)s2 * 64 + lane], sc, sh), 0.f);
            acc3 += fmaxf(fmaf(h[(size_t)s3 * 64 + lane], sc, sh), 0.f);
        }
        for (; jj < m; jj++) {
            int s = __shfl(myidx, jj, 64);
            acc0 += fmaxf(fmaf(h[(size_t)s * 64 + lane], sc, sh), 0.f);
        }
    }
    agg[(size_t)w * 64 + lane] = acc0 + acc1 + acc2 + acc3;
}

// ---- channel-split 64x64 matmul: 2 lanes per node (32 ch each), fused
//      input-side BN+ReLU for the self term. 128 nodes/block, grid 782. -----
__global__ __launch_bounds__(256) void mm64_bn_split(
    const float* __restrict__ agg, const float* __restrict__ hraw,
    const int* __restrict__ rowptr,
    const float* __restrict__ stats, const float* __restrict__ g,
    const float* __restrict__ be,
    const float* __restrict__ Wl, const float* __restrict__ bias,
    const float* __restrict__ Wr,
    float* __restrict__ out, float invN, int n)
{
    __shared__ float4 sWl[64 * 16];
    __shared__ float4 sWr[64 * 16];
    __shared__ float  ssc[64], ssh[64];
    int t = threadIdx.x;
    for (int i = t; i < 64 * 16; i += 256) {
        sWl[i] = ((const float4*)Wl)[i];
        sWr[i] = ((const float4*)Wr)[i];
    }
    if (t < 64) {
        float mu  = stats[t] * invN;
        float var = stats[64 + t] * invN - mu * mu;
        float sc  = g[t] / sqrtf(var + EPS_BN);
        ssc[t] = sc;
        ssh[t] = fmaf(-mu, sc, be[t]);
    }
    __syncthreads();

    int wv = t >> 6, lane = t & 63;
    int half = lane >> 5;                       // 0: ch 0-31, 1: ch 32-63
    int node = blockIdx.x * 128 + wv * 32 + (lane & 31);
    if (node >= n) return;

    float invd = 1.0f / fmaxf((float)(rowptr[node + 1] - rowptr[node]), 1.0f);
    int cg0 = half * 8;

    float4 acc[8];
#pragma unroll
    for (int q = 0; q < 8; q++) acc[q] = ((const float4*)bias)[cg0 + q];

    const float4* ar = (const float4*)(agg  + (size_t)node * 64);
    const float4* hr = (const float4*)(hraw + (size_t)node * 64);

#pragma unroll 1
    for (int k4 = 0; k4 < 16; k4++) {
        float4 a = ar[k4], h = hr[k4];
        float aa[4] = {a.x, a.y, a.z, a.w}, hh[4] = {h.x, h.y, h.z, h.w};
#pragma unroll
        for (int j = 0; j < 4; j++) {
            int k = k4 * 4 + j;
            float am = aa[j] * invd;
            float hk = fmaxf(fmaf(hh[j], ssc[k], ssh[k]), 0.f);
#pragma unroll
            for (int q = 0; q < 8; q++) {
                float4 wl = sWl[k * 16 + cg0 + q];
                float4 wr = sWr[k * 16 + cg0 + q];
                acc[q].x = fmaf(am, wl.x, fmaf(hk, wr.x, acc[q].x));
                acc[q].y = fmaf(am, wl.y, fmaf(hk, wr.y, acc[q].y));
                acc[q].z = fmaf(am, wl.z, fmaf(hk, wr.z, acc[q].z));
                acc[q].w = fmaf(am, wl.w, fmaf(hk, wr.w, acc[q].w));
            }
        }
    }
    float4* o = (float4*)(out + (size_t)node * 64) + cg0;
#pragma unroll
    for (int q = 0; q < 8; q++) o[q] = acc[q];
}

// ---- BN stats (separate pass — R5 verbatim) -------------------------------
__global__ __launch_bounds__(256) void bn_stats(const float* __restrict__ h,
                                                float* __restrict__ stats, size_t total)
{
    __shared__ float ls[64], lss[64];
    if (threadIdx.x < 64) { ls[threadIdx.x] = 0.f; lss[threadIdx.x] = 0.f; }
    __syncthreads();
    float s = 0.f, ss = 0.f;
    size_t stride = (size_t)gridDim.x * 256;
    for (size_t i = (size_t)blockIdx.x * 256 + threadIdx.x; i < total; i += stride) {
        float v = h[i];
        s += v;
        ss = fmaf(v, v, ss);
    }
    int c = threadIdx.x & 63;
    atomicAdd(&ls[c], s);
    atomicAdd(&lss[c], ss);
    __syncthreads();
    if (threadIdx.x < 64) {
        unsafeAtomicAdd(&stats[threadIdx.x], ls[threadIdx.x]);
        unsafeAtomicAdd(&stats[64 + threadIdx.x], lss[threadIdx.x]);
    }
}

// ---- fused layer-3 BN+ReLU + attention-weighted segment pooling -----------
__global__ __launch_bounds__(256) void bn_pool(
    const float* __restrict__ h, const float* __restrict__ stats,
    const float* __restrict__ g, const float* __restrict__ be,
    const float* __restrict__ x, const int* __restrict__ batch,
    float* __restrict__ rawpool, float invN, int N, int chunk)
{
    int wid  = blockIdx.x * 4 + (threadIdx.x >> 6);
    int lane = threadIdx.x & 63;
    int i0 = wid * chunk;
    if (i0 >= N) return;
    int i1 = min(i0 + chunk, N);

    float mu  = stats[lane] * invN;
    float var = stats[64 + lane] * invN - mu * mu;
    float sc  = g[lane] / sqrtf(var + EPS_BN);
    float sh  = fmaf(-mu, sc, be[lane]);

    int   cur = batch[i0];
    float acc = 0.f;
    for (int i = i0; i < i1; i++) {
        int bi = batch[i];
        if (bi != cur) {
            unsafeAtomicAdd(&rawpool[cur * 64 + lane], acc);
            acc = 0.f;
            cur = bi;
        }
        float w = expf(x[(size_t)i * 6 + 4]);
        float v = fmaxf(fmaf(h[(size_t)i * 64 + lane], sc, sh), 0.f);
        acc = fmaf(v, w, acc);
    }
    unsafeAtomicAdd(&rawpool[cur * 64 + lane], acc);
}

// ---- softmax denominator (shift-invariant: min-sub + 1e-8 drop out) -------
__global__ __launch_bounds__(256) void softmax_sum(const float* __restrict__ x,
                                                   float* __restrict__ sumexp, int n)
{
    float s = 0.f;
    int stride = gridDim.x * 256;
    for (int i = blockIdx.x * 256 + threadIdx.x; i < n; i += stride)
        s += expf(x[(size_t)i * 6 + 4]);
#pragma unroll
    for (int o = 32; o > 0; o >>= 1) s += __shfl_down(s, o, 64);
    __shared__ float wsum[4];
    if ((threadIdx.x & 63) == 0) wsum[threadIdx.x >> 6] = s;
    __syncthreads();
    if (threadIdx.x == 0)
        unsafeAtomicAdd(sumexp, wsum[0] + wsum[1] + wsum[2] + wsum[3]);
}

__global__ void seg_bounds(const int* __restrict__ batch, int* __restrict__ lb, int n)
{
    int b = threadIdx.x;
    if (b > 64) return;
    int lo = 0, hi = n;
    while (lo < hi) {
        int mid = (lo + hi) >> 1;
        if (batch[mid] < b) lo = mid + 1; else hi = mid;
    }
    lb[b] = lo;
}

// ---- heads: normalize rawpool by 1/sumexp and counts, then 2 tiny MLPs ----
__global__ __launch_bounds__(64) void heads_kernel(
    const float* __restrict__ rawpool, const float* __restrict__ sumexp,
    const int* __restrict__ lb,
    const float* __restrict__ phW1, const float* __restrict__ phb1,
    const float* __restrict__ phW2, const float* __restrict__ phb2,
    const float* __restrict__ trW1, const float* __restrict__ trb1,
    const float* __restrict__ trW2, const float* __restrict__ trb2,
    float* __restrict__ out)
{
    int b = blockIdx.x, t = threadIdx.x;
    __shared__ float p[64], h1[32], h2[16];
    float cnt = (float)(lb[b + 1] - lb[b]);
    p[t] = rawpool[b * 64 + t] / (sumexp[0] * fmaxf(cnt, 1.0f));
    __syncthreads();
    if (t < 32) {
        float s = phb1[t];
        for (int k = 0; k < 64; k++) s = fmaf(p[k], phW1[k * 32 + t], s);
        h1[t] = fmaxf(s, 0.f);
    } else if (t < 48) {
        int tt = t - 32;
        float s = trb1[tt];
        for (int k = 0; k < 64; k++) s = fmaf(p[k], trW1[k * 16 + tt], s);
        h2[tt] = fmaxf(s, 0.f);
    }
    __syncthreads();
    if (t < 3) {
        float s = phb2[t];
        for (int k = 0; k < 32; k++) s = fmaf(h1[k], phW2[k * 3 + t], s);
        out[b * 3 + t] = s;
    } else if (t == 63) {
        float s = trb2[0];
        for (int k = 0; k < 16; k++) s = fmaf(h2[k], trW2[k], s);
        out[192 + b] = 1.0f / (1.0f + expf(-s));
    }
}

extern "C" void kernel_launch(void* const* d_in, const int* in_sizes, int n_in,
                              void* d_out, int out_size, void* d_ws, size_t ws_size,
                              hipStream_t stream)
{
    const float* x     = (const float*)d_in[0];
    const int*   ei    = (const int*)d_in[1];
    const int*   batch = (const int*)d_in[2];
    const float* W1l = (const float*)d_in[3];
    const float* b1  = (const float*)d_in[4];
    const float* W1r = (const float*)d_in[5];
    const float* W2l = (const float*)d_in[6];
    const float* b2  = (const float*)d_in[7];
    const float* W2r = (const float*)d_in[8];
    const float* W3l = (const float*)d_in[9];
    const float* b3  = (const float*)d_in[10];
    const float* W3r = (const float*)d_in[11];
    const float* g1  = (const float*)d_in[12];
    const float* be1 = (const float*)d_in[13];
    const float* g2  = (const float*)d_in[14];
    const float* be2 = (const float*)d_in[15];
    const float* g3  = (const float*)d_in[16];
    const float* be3 = (const float*)d_in[17];
    const float* phW1 = (const float*)d_in[18];
    const float* phb1 = (const float*)d_in[19];
    const float* phW2 = (const float*)d_in[20];
    const float* phb2 = (const float*)d_in[21];
    const float* trW1 = (const float*)d_in[22];
    const float* trb1 = (const float*)d_in[23];
    const float* trW2 = (const float*)d_in[24];
    const float* trb2 = (const float*)d_in[25];

    const int N = in_sizes[0] / 6;
    const int E = in_sizes[1] / 2;
    const int* src = ei;
    const int* dst = ei + E;

    const int NB    = (N + 255) >> 8;          // 391 buckets
    const int nBlkA = (E + EPB - 1) / EPB;     // 196 partition blocks

    float* ws = (float*)d_ws;
    const size_t N64 = (size_t)N * 64;
    float* agg      = ws;                          // N*64
    float* hA       = ws + N64;                    // N*64 (h1 raw, then h3 raw)
    float* hB       = ws + 2 * N64;                // N*64 (h2 raw)
    int*   epck     = (int*)(ws + 3 * N64);        // E packed src|dl<<24
    int*   eidx     = epck + E;                    // E (CSR by dst)
    int*   blockBin = eidx + E;                    // nBlkA * NBIN
    // --- contiguous zero region: binTotal + stats[3][128] + rawpool + sumexp
    int*   binTotal = blockBin + (size_t)nBlkA * NBIN;   // NBIN
    float* stats    = (float*)(binTotal + NBIN);   // 3 * 128
    float* rawpool  = stats + 384;                 // 64*64
    float* sumexp   = rawpool + 4096;              // 1 (pad 4)
    // --- end zero region ---
    int*   binBase  = (int*)(sumexp + 4);          // NBIN + 1
    int*   rowptr   = binBase + NBIN + 1;          // N + 1
    int*   lb       = rowptr + N + 1;              // 65 (pad 72)
    float* out      = (float*)d_out;

    const int nodeBlocks = (N + 255) / 256;
    const int waveNodeBlocks = (int)(((size_t)N * 64 + 255) / 256);
    const int mmBlocks = (N + 127) / 128;          // 782
    const int PBLK = 1024;                         // bn_pool blocks (4 waves each)
    const int chunk = (N + PBLK * 4 - 1) / (PBLK * 4);
    const float invN = 1.0f / (float)N;

    // ---- zero accumulators; independent reductions first ----
    size_t zbytes = (char*)(sumexp + 4) - (char*)binTotal;
    hipMemsetAsync(binTotal, 0, zbytes, stream);
    softmax_sum<<<256, 256, 0, stream>>>(x, sumexp, N);
    seg_bounds<<<1, 128, 0, stream>>>(batch, lb, N);

    // ---- CSR build via bucket partition ----
    bucket_hist<<<nBlkA, 256, 0, stream>>>(dst, blockBin, binTotal, E);
    bin_scan<<<1, NBIN, 0, stream>>>(binTotal, binBase, blockBin, rowptr + N, nBlkA);
    bucket_scatter<<<nBlkA, 256, 0, stream>>>(src, dst, blockBin, epck, E);
    csr_local<<<NB, 256, 0, stream>>>(epck, binBase, rowptr, eidx, N);

    // ---- layer 1: agg6 + matmul -> hA raw; stats1 ----
    sage1_fused<<<nodeBlocks, 256, 0, stream>>>(rowptr, eidx, x, W1l, b1, W1r, hA, N);
    bn_stats<<<1024, 256, 0, stream>>>(hA, stats, N64);

    // ---- layer 2: BN1 applied on the fly (neighbors in aggpull, self in mm)
    aggpull64_bn<<<waveNodeBlocks, 256, 0, stream>>>(rowptr, eidx, hA, stats,
                                                     g1, be1, agg, invN, N);
    mm64_bn_split<<<mmBlocks, 256, 0, stream>>>(agg, hA, rowptr, stats, g1, be1,
                                                W2l, b2, W2r, hB, invN, N);
    bn_stats<<<1024, 256, 0, stream>>>(hB, stats + 128, N64);

    // ---- layer 3: BN2 on the fly ----
    aggpull64_bn<<<waveNodeBlocks, 256, 0, stream>>>(rowptr, eidx, hB, stats + 128,
                                                     g2, be2, agg, invN, N);
    mm64_bn_split<<<mmBlocks, 256, 0, stream>>>(agg, hB, rowptr, stats + 128, g2, be2,
                                                W3l, b3, W3r, hA, invN, N);
    bn_stats<<<1024, 256, 0, stream>>>(hA, stats + 256, N64);

    // ---- fused BN3 + attention pooling + heads ----
    bn_pool<<<PBLK, 256, 0, stream>>>(hA, stats + 256, g3, be3, x, batch,
                                      rawpool, invN, N, chunk);
    heads_kernel<<<64, 64, 0, stream>>>(rawpool, sumexp, lb,
                                        phW1, phb1, phW2, phb2,
                                        trW1, trb1, trW2, trb2, out);
}

// Round 9
// 529.312 us; speedup vs baseline: 2.8519x; 1.1208x over previous
//
#include <hip/hip_runtime.h>
#include <hip/hip_fp16.h>
#include <cstdint>
#include <cstddef>

// ---------------------------------------------------------------------------
// TopoGNN: 3x SAGEConv(mean) + BN + ReLU, softmax-attention pooling, 2 heads.
// N=100000 nodes, E=1600000 edges, B=64 segments, IN_CH=6, HID=64.
// R5 (754us): bucket partition + per-bucket local CSR + register pull.
// R7 (644us): + bn_pool (fused BN3+attention pooling).
// R8 (593us): channel-split matmul (782 blocks) + BN-on-the-fly; top is now
//     aggpull64_bn 63us: FETCH 177MB, 3.3TB/s, genuinely gather-BW-bound.
// R9: fp16 normalized h (bn16 pass) -> gather bytes halve (128B rows), agg16
//     fp16; mm64_h16 pure GEMM on fp16 inputs; bin_scan's serial 196-step
//     blockBin walk parallelized (wave-per-bin shfl scan).
// ---------------------------------------------------------------------------

#define EPB 8192   // edges per partition block (256 thr x 32)
#define NBIN 512   // padded bucket count (actual NB = ceil(N/256) <= 512)
#define EPS_BN 1e-5f

// ---- phase A: per-block bucket histogram ---------------------------------
__global__ __launch_bounds__(256) void bucket_hist(const int* __restrict__ dst,
                                                   int* __restrict__ blockBin,
                                                   int* __restrict__ binTotal, int E)
{
    __shared__ int hist[NBIN];
    int t = threadIdx.x;
    for (int i = t; i < NBIN; i += 256) hist[i] = 0;
    __syncthreads();
    int e0 = blockIdx.x * EPB;
#pragma unroll
    for (int k = 0; k < 32; k++) {
        int e = e0 + (k << 8) + t;
        if (e < E) atomicAdd(&hist[dst[e] >> 8], 1);
    }
    __syncthreads();
    for (int i = t; i < NBIN; i += 256) {
        int c = hist[i];
        blockBin[blockIdx.x * NBIN + i] = c;
        if (c) atomicAdd(&binTotal[i], c);
    }
}

// ---- phase B1: single-block scan of the 512 bin totals --------------------
__global__ __launch_bounds__(512) void bin_scan_totals(const int* __restrict__ binTotal,
                                                       int* __restrict__ binBase,
                                                       int* __restrict__ rowptrN)
{
    __shared__ int s[NBIN];
    int t = threadIdx.x;
    int tot = binTotal[t];
    s[t] = tot;
    __syncthreads();
    for (int off = 1; off < NBIN; off <<= 1) {
        int v = (t >= off) ? s[t - off] : 0;
        __syncthreads();
        s[t] += v;
        __syncthreads();
    }
    binBase[t] = s[t] - tot;
    if (t == NBIN - 1) { binBase[NBIN] = s[t]; *rowptrN = s[t]; }
}

// ---- phase B2: per-bin exclusive scan over block counts (wave per bin) ----
__global__ __launch_bounds__(256) void blockbin_offs(int* __restrict__ blockBin,
                                                     const int* __restrict__ binBase,
                                                     int nBlk)
{
    int wv   = threadIdx.x >> 6;
    int lane = threadIdx.x & 63;
    int bin  = blockIdx.x * 4 + wv;
    int carry = binBase[bin];
    for (int c0 = 0; c0 < nBlk; c0 += 64) {
        int blk = c0 + lane;
        int cnt = (blk < nBlk) ? blockBin[blk * NBIN + bin] : 0;
        int v = cnt;
#pragma unroll
        for (int d = 1; d < 64; d <<= 1) {
            int u = __shfl_up(v, d, 64);
            if (lane >= d) v += u;
        }
        if (blk < nBlk) blockBin[blk * NBIN + bin] = carry + v - cnt;
        carry += __shfl(v, 63, 64);
    }
}

// ---- phase C: place packed (src | local_dst<<24); per-block LDS cursors ---
__global__ __launch_bounds__(256) void bucket_scatter(const int* __restrict__ src,
                                                      const int* __restrict__ dst,
                                                      const int* __restrict__ blockBin,
                                                      int* __restrict__ epck, int E)
{
    __shared__ int cur[NBIN];
    int t = threadIdx.x;
    for (int i = t; i < NBIN; i += 256) cur[i] = blockBin[blockIdx.x * NBIN + i];
    __syncthreads();
    int e0 = blockIdx.x * EPB;
#pragma unroll
    for (int k = 0; k < 32; k++) {
        int e = e0 + (k << 8) + t;
        if (e < E) {
            int d = dst[e];
            int pos = atomicAdd(&cur[d >> 8], 1);
            epck[pos] = src[e] | ((d & 255) << 24);   // src < 2^24
        }
    }
}

// ---- phase D: per-bucket local CSR --------------------------------------
__global__ __launch_bounds__(256) void csr_local(const int* __restrict__ epck,
                                                 const int* __restrict__ binBase,
                                                 int* __restrict__ rowptr,
                                                 int* __restrict__ eidx, int N)
{
    __shared__ int cnt[256], s[256], cur[256];
    int t = threadIdx.x, bkt = blockIdx.x;
    int base = binBase[bkt], nE = binBase[bkt + 1] - base;
    cnt[t] = 0;
    __syncthreads();
    for (int j = t; j < nE; j += 256)
        atomicAdd(&cnt[(unsigned)epck[base + j] >> 24], 1);
    __syncthreads();
    s[t] = cnt[t];
    __syncthreads();
    for (int off = 1; off < 256; off <<= 1) {
        int v = (t >= off) ? s[t - off] : 0;
        __syncthreads();
        s[t] += v;
        __syncthreads();
    }
    int excl = s[t] - cnt[t];
    cur[t] = excl;
    int node = (bkt << 8) + t;
    if (node < N) rowptr[node] = base + excl;
    __syncthreads();
    for (int j = t; j < nE; j += 256) {
        int v = epck[base + j];
        int pos = atomicAdd(&cur[(unsigned)v >> 24], 1);
        eidx[base + pos] = v & 0xFFFFFF;     // contiguous 16KB span: stays in L2
    }
}

// ---- layer 1: fused pull-aggregation (6 ch) + matmul ----------------------
__global__ __launch_bounds__(256) void sage1_fused(
    const int* __restrict__ rowptr, const int* __restrict__ eidx,
    const float* __restrict__ x,
    const float* __restrict__ Wl, const float* __restrict__ bias,
    const float* __restrict__ Wr, float* __restrict__ out, int n)
{
    __shared__ float4 sWl[6 * 16];
    __shared__ float4 sWr[6 * 16];
    for (int i = threadIdx.x; i < 6 * 16; i += 256) {
        sWl[i] = ((const float4*)Wl)[i];
        sWr[i] = ((const float4*)Wr)[i];
    }
    __syncthreads();

    int node = blockIdx.x * 256 + threadIdx.x;
    if (node >= n) return;

    int b = rowptr[node], e = rowptr[node + 1];
    float a[6] = {0.f, 0.f, 0.f, 0.f, 0.f, 0.f};
    for (int j = b; j < e; j++) {
        int s = eidx[j];
        const float2* r = (const float2*)(x + (size_t)s * 6);
        float2 r0 = r[0], r1 = r[1], r2 = r[2];
        a[0] += r0.x; a[1] += r0.y; a[2] += r1.x;
        a[3] += r1.y; a[4] += r2.x; a[5] += r2.y;
    }
    float invd = 1.0f / fmaxf((float)(e - b), 1.0f);

    const float2* xr2 = (const float2*)(x + (size_t)node * 6);
    float2 x0 = xr2[0], x1 = xr2[1], x2 = xr2[2];
    float hh[6] = {x0.x, x0.y, x1.x, x1.y, x2.x, x2.y};

    float4 acc[16];
#pragma unroll
    for (int cg = 0; cg < 16; cg++) acc[cg] = ((const float4*)bias)[cg];
#pragma unroll
    for (int k = 0; k < 6; k++) {
        float am = a[k] * invd;
        float hk = hh[k];
#pragma unroll
        for (int cg = 0; cg < 16; cg++) {
            float4 wl = sWl[k * 16 + cg];
            float4 wr = sWr[k * 16 + cg];
            acc[cg].x = fmaf(am, wl.x, fmaf(hk, wr.x, acc[cg].x));
            acc[cg].y = fmaf(am, wl.y, fmaf(hk, wr.y, acc[cg].y));
            acc[cg].z = fmaf(am, wl.z, fmaf(hk, wr.z, acc[cg].z));
            acc[cg].w = fmaf(am, wl.w, fmaf(hk, wr.w, acc[cg].w));
        }
    }
    float4* orow = (float4*)(out + (size_t)node * 64);
#pragma unroll
    for (int cg = 0; cg < 16; cg++) orow[cg] = acc[cg];
}

// ---- BN stats (separate pass) ---------------------------------------------
__global__ __launch_bounds__(256) void bn_stats(const float* __restrict__ h,
                                                float* __restrict__ stats, size_t total)
{
    __shared__ float ls[64], lss[64];
    if (threadIdx.x < 64) { ls[threadIdx.x] = 0.f; lss[threadIdx.x] = 0.f; }
    __syncthreads();
    float s = 0.f, ss = 0.f;
    size_t stride = (size_t)gridDim.x * 256;
    for (size_t i = (size_t)blockIdx.x * 256 + threadIdx.x; i < total; i += stride) {
        float v = h[i];
        s += v;
        ss = fmaf(v, v, ss);
    }
    int c = threadIdx.x & 63;
    atomicAdd(&ls[c], s);
    atomicAdd(&lss[c], ss);
    __syncthreads();
    if (threadIdx.x < 64) {
        unsafeAtomicAdd(&stats[threadIdx.x], ls[threadIdx.x]);
        unsafeAtomicAdd(&stats[64 + threadIdx.x], lss[threadIdx.x]);
    }
}

// ---- bn16: h16 = fp16(relu(bn(h))), half2 per thread ----------------------
__global__ __launch_bounds__(256) void bn16(const float* __restrict__ h,
                                            const float* __restrict__ stats,
                                            const float* __restrict__ g,
                                            const float* __restrict__ be,
                                            __half* __restrict__ h16,
                                            float invN, size_t total)
{
    size_t i2 = (size_t)blockIdx.x * 256 + threadIdx.x;
    if (i2 * 2 >= total) return;
    size_t i = i2 * 2;
    int c = (int)(i & 63);          // even
    float mu0  = stats[c] * invN;
    float var0 = stats[64 + c] * invN - mu0 * mu0;
    float sc0  = g[c] / sqrtf(var0 + EPS_BN);
    float sh0  = fmaf(-mu0, sc0, be[c]);
    float mu1  = stats[c + 1] * invN;
    float var1 = stats[64 + c + 1] * invN - mu1 * mu1;
    float sc1  = g[c + 1] / sqrtf(var1 + EPS_BN);
    float sh1  = fmaf(-mu1, sc1, be[c + 1]);
    float2 hv = ((const float2*)h)[i2];
    float v0 = fmaxf(fmaf(hv.x, sc0, sh0), 0.f);
    float v1 = fmaxf(fmaf(hv.y, sc1, sh1), 0.f);
    ((__half2*)h16)[i2] = __floats2half2_rn(v0, v1);
}

// ---- pull aggregation on fp16 rows; writes fp16 mean ----------------------
__global__ __launch_bounds__(256) void aggpull16(const int* __restrict__ rowptr,
                                                 const int* __restrict__ eidx,
                                                 const __half* __restrict__ h16,
                                                 __half* __restrict__ agg16, int n)
{
    int w    = (blockIdx.x * 256 + threadIdx.x) >> 6;
    int lane = threadIdx.x & 63;
    if (w >= n) return;
    int b = rowptr[w], e = rowptr[w + 1];
    float acc0 = 0.f, acc1 = 0.f, acc2 = 0.f, acc3 = 0.f;
    for (int j0 = b; j0 < e; j0 += 64) {
        int myidx = (j0 + lane < e) ? eidx[j0 + lane] : 0;
        int m = min(64, e - j0);
        int jj = 0;
        for (; jj + 4 <= m; jj += 4) {
            int s0 = __shfl(myidx, jj,     64);
            int s1 = __shfl(myidx, jj + 1, 64);
            int s2 = __shfl(myidx, jj + 2, 64);
            int s3 = __shfl(myidx, jj + 3, 64);
            acc0 += __half2float(h16[(size_t)s0 * 64 + lane]);
            acc1 += __half2float(h16[(size_t)s1 * 64 + lane]);
            acc2 += __half2float(h16[(size_t)s2 * 64 + lane]);
            acc3 += __half2float(h16[(size_t)s3 * 64 + lane]);
        }
        for (; jj < m; jj++) {
            int s = __shfl(myidx, jj, 64);
            acc0 += __half2float(h16[(size_t)s * 64 + lane]);
        }
    }
    float invd = 1.0f / fmaxf((float)(e - b), 1.0f);
    agg16[(size_t)w * 64 + lane] = __float2half_rn((acc0 + acc1 + acc2 + acc3) * invd);
}

// ---- channel-split 64x64 GEMM on fp16 inputs (BN/mean pre-folded) ---------
__global__ __launch_bounds__(256) void mm64_h16(
    const __half* __restrict__ agg16, const __half* __restrict__ h16,
    const float* __restrict__ Wl, const float* __restrict__ bias,
    const float* __restrict__ Wr, float* __restrict__ out, int n)
{
    __shared__ float4 sWl[64 * 16];
    __shared__ float4 sWr[64 * 16];
    int t = threadIdx.x;
    for (int i = t; i < 64 * 16; i += 256) {
        sWl[i] = ((const float4*)Wl)[i];
        sWr[i] = ((const float4*)Wr)[i];
    }
    __syncthreads();

    int wv = t >> 6, lane = t & 63;
    int half = lane >> 5;                       // 0: ch 0-31, 1: ch 32-63
    int node = blockIdx.x * 128 + wv * 32 + (lane & 31);
    if (node >= n) return;
    int cg0 = half * 8;

    float4 acc[8];
#pragma unroll
    for (int q = 0; q < 8; q++) acc[q] = ((const float4*)bias)[cg0 + q];

    const float2* ar = (const float2*)(agg16 + (size_t)node * 64);  // 4 halves per float2
    const float2* hr = (const float2*)(h16   + (size_t)node * 64);

#pragma unroll 1
    for (int k4 = 0; k4 < 16; k4++) {
        float2 af = ar[k4], hf = hr[k4];
        __half2 a01 = ((const __half2*)&af)[0], a23 = ((const __half2*)&af)[1];
        __half2 h01 = ((const __half2*)&hf)[0], h23 = ((const __half2*)&hf)[1];
        float aa[4] = {__low2float(a01), __high2float(a01),
                       __low2float(a23), __high2float(a23)};
        float hh[4] = {__low2float(h01), __high2float(h01),
                       __low2float(h23), __high2float(h23)};
#pragma unroll
        for (int j = 0; j < 4; j++) {
            int k = k4 * 4 + j;
            float am = aa[j];
            float hk = hh[j];
#pragma unroll
            for (int q = 0; q < 8; q++) {
                float4 wl = sWl[k * 16 + cg0 + q];
                float4 wr = sWr[k * 16 + cg0 + q];
                acc[q].x = fmaf(am, wl.x, fmaf(hk, wr.x, acc[q].x));
                acc[q].y = fmaf(am, wl.y, fmaf(hk, wr.y, acc[q].y));
                acc[q].z = fmaf(am, wl.z, fmaf(hk, wr.z, acc[q].z));
                acc[q].w = fmaf(am, wl.w, fmaf(hk, wr.w, acc[q].w));
            }
        }
    }
    float4* o = (float4*)(out + (size_t)node * 64) + cg0;
#pragma unroll
    for (int q = 0; q < 8; q++) o[q] = acc[q];
}

// ---- fused layer-3 BN+ReLU + attention-weighted segment pooling -----------
__global__ __launch_bounds__(256) void bn_pool(
    const float* __restrict__ h, const float* __restrict__ stats,
    const float* __restrict__ g, const float* __restrict__ be,
    const float* __restrict__ x, const int* __restrict__ batch,
    float* __restrict__ rawpool, float invN, int N, int chunk)
{
    int wid  = blockIdx.x * 4 + (threadIdx.x >> 6);
    int lane = threadIdx.x & 63;
    int i0 = wid * chunk;
    if (i0 >= N) return;
    int i1 = min(i0 + chunk, N);

    float mu  = stats[lane] * invN;
    float var = stats[64 + lane] * invN - mu * mu;
    float sc  = g[lane] / sqrtf(var + EPS_BN);
    float sh  = fmaf(-mu, sc, be[lane]);

    int   cur = batch[i0];
    float acc = 0.f;
    for (int i = i0; i < i1; i++) {
        int bi = batch[i];
        if (bi != cur) {
            unsafeAtomicAdd(&rawpool[cur * 64 + lane], acc);
            acc = 0.f;
            cur = bi;
        }
        float w = expf(x[(size_t)i * 6 + 4]);
        float v = fmaxf(fmaf(h[(size_t)i * 64 + lane], sc, sh), 0.f);
        acc = fmaf(v, w, acc);
    }
    unsafeAtomicAdd(&rawpool[cur * 64 + lane], acc);
}

// ---- softmax denominator (shift-invariant: min-sub + 1e-8 drop out) -------
__global__ __launch_bounds__(256) void softmax_sum(const float* __restrict__ x,
                                                   float* __restrict__ sumexp, int n)
{
    float s = 0.f;
    int stride = gridDim.x * 256;
    for (int i = blockIdx.x * 256 + threadIdx.x; i < n; i += stride)
        s += expf(x[(size_t)i * 6 + 4]);
#pragma unroll
    for (int o = 32; o > 0; o >>= 1) s += __shfl_down(s, o, 64);
    __shared__ float wsum[4];
    if ((threadIdx.x & 63) == 0) wsum[threadIdx.x >> 6] = s;
    __syncthreads();
    if (threadIdx.x == 0)
        unsafeAtomicAdd(sumexp, wsum[0] + wsum[1] + wsum[2] + wsum[3]);
}

__global__ void seg_bounds(const int* __restrict__ batch, int* __restrict__ lb, int n)
{
    int b = threadIdx.x;
    if (b > 64) return;
    int lo = 0, hi = n;
    while (lo < hi) {
        int mid = (lo + hi) >> 1;
        if (batch[mid] < b) lo = mid + 1; else hi = mid;
    }
    lb[b] = lo;
}

// ---- heads: normalize rawpool by 1/sumexp and counts, then 2 tiny MLPs ----
__global__ __launch_bounds__(64) void heads_kernel(
    const float* __restrict__ rawpool, const float* __restrict__ sumexp,
    const int* __restrict__ lb,
    const float* __restrict__ phW1, const float* __restrict__ phb1,
    const float* __restrict__ phW2, const float* __restrict__ phb2,
    const float* __restrict__ trW1, const float* __restrict__ trb1,
    const float* __restrict__ trW2, const float* __restrict__ trb2,
    float* __restrict__ out)
{
    int b = blockIdx.x, t = threadIdx.x;
    __shared__ float p[64], h1[32], h2[16];
    float cnt = (float)(lb[b + 1] - lb[b]);
    p[t] = rawpool[b * 64 + t] / (sumexp[0] * fmaxf(cnt, 1.0f));
    __syncthreads();
    if (t < 32) {
        float s = phb1[t];
        for (int k = 0; k < 64; k++) s = fmaf(p[k], phW1[k * 32 + t], s);
        h1[t] = fmaxf(s, 0.f);
    } else if (t < 48) {
        int tt = t - 32;
        float s = trb1[tt];
        for (int k = 0; k < 64; k++) s = fmaf(p[k], trW1[k * 16 + tt], s);
        h2[tt] = fmaxf(s, 0.f);
    }
    __syncthreads();
    if (t < 3) {
        float s = phb2[t];
        for (int k = 0; k < 32; k++) s = fmaf(h1[k], phW2[k * 3 + t], s);
        out[b * 3 + t] = s;
    } else if (t == 63) {
        float s = trb2[0];
        for (int k = 0; k < 16; k++) s = fmaf(h2[k], trW2[k], s);
        out[192 + b] = 1.0f / (1.0f + expf(-s));
    }
}

extern "C" void kernel_launch(void* const* d_in, const int* in_sizes, int n_in,
                              void* d_out, int out_size, void* d_ws, size_t ws_size,
                              hipStream_t stream)
{
    const float* x     = (const float*)d_in[0];
    const int*   ei    = (const int*)d_in[1];
    const int*   batch = (const int*)d_in[2];
    const float* W1l = (const float*)d_in[3];
    const float* b1  = (const float*)d_in[4];
    const float* W1r = (const float*)d_in[5];
    const float* W2l = (const float*)d_in[6];
    const float* b2  = (const float*)d_in[7];
    const float* W2r = (const float*)d_in[8];
    const float* W3l = (const float*)d_in[9];
    const float* b3  = (const float*)d_in[10];
    const float* W3r = (const float*)d_in[11];
    const float* g1  = (const float*)d_in[12];
    const float* be1 = (const float*)d_in[13];
    const float* g2  = (const float*)d_in[14];
    const float* be2 = (const float*)d_in[15];
    const float* g3  = (const float*)d_in[16];
    const float* be3 = (const float*)d_in[17];
    const float* phW1 = (const float*)d_in[18];
    const float* phb1 = (const float*)d_in[19];
    const float* phW2 = (const float*)d_in[20];
    const float* phb2 = (const float*)d_in[21];
    const float* trW1 = (const float*)d_in[22];
    const float* trb1 = (const float*)d_in[23];
    const float* trW2 = (const float*)d_in[24];
    const float* trb2 = (const float*)d_in[25];

    const int N = in_sizes[0] / 6;
    const int E = in_sizes[1] / 2;
    const int* src = ei;
    const int* dst = ei + E;

    const int NB    = (N + 255) >> 8;          // 391 buckets
    const int nBlkA = (E + EPB - 1) / EPB;     // 196 partition blocks

    float* ws = (float*)d_ws;
    const size_t N64 = (size_t)N * 64;
    float*  hA      = ws;                          // N*64 fp32 (h1 raw, then h3 raw)
    float*  hB      = ws + N64;                    // N*64 fp32 (h2 raw)
    __half* agg16   = (__half*)(ws + 2 * N64);     // N*64 fp16
    __half* h16     = (__half*)(ws + 2 * N64 + N64 / 2);  // N*64 fp16 (reused L2/L3)
    int*   epck     = (int*)(ws + 3 * N64);        // E packed src|dl<<24
    int*   eidx     = epck + E;                    // E (CSR by dst)
    int*   blockBin = eidx + E;                    // nBlkA * NBIN
    // --- contiguous zero region: binTotal + stats[3][128] + rawpool + sumexp
    int*   binTotal = blockBin + (size_t)nBlkA * NBIN;   // NBIN
    float* stats    = (float*)(binTotal + NBIN);   // 3 * 128
    float* rawpool  = stats + 384;                 // 64*64
    float* sumexp   = rawpool + 4096;              // 1 (pad 4)
    // --- end zero region ---
    int*   binBase  = (int*)(sumexp + 4);          // NBIN + 1
    int*   rowptr   = binBase + NBIN + 1;          // N + 1
    int*   lb       = rowptr + N + 1;              // 65 (pad 72)
    float* out      = (float*)d_out;

    const int nodeBlocks = (N + 255) / 256;
    const int waveNodeBlocks = (int)(((size_t)N * 64 + 255) / 256);
    const int mmBlocks = (N + 127) / 128;          // 782
    const int cvtBlocks = (int)((N64 / 2 + 255) / 256);
    const int PBLK = 1024;                         // bn_pool blocks (4 waves each)
    const int chunk = (N + PBLK * 4 - 1) / (PBLK * 4);
    const float invN = 1.0f / (float)N;

    // ---- zero accumulators; independent reductions first ----
    size_t zbytes = (char*)(sumexp + 4) - (char*)binTotal;
    hipMemsetAsync(binTotal, 0, zbytes, stream);
    softmax_sum<<<256, 256, 0, stream>>>(x, sumexp, N);
    seg_bounds<<<1, 128, 0, stream>>>(batch, lb, N);

    // ---- CSR build via bucket partition ----
    bucket_hist<<<nBlkA, 256, 0, stream>>>(dst, blockBin, binTotal, E);
    bin_scan_totals<<<1, NBIN, 0, stream>>>(binTotal, binBase, rowptr + N);
    blockbin_offs<<<NBIN / 4, 256, 0, stream>>>(blockBin, binBase, nBlkA);
    bucket_scatter<<<nBlkA, 256, 0, stream>>>(src, dst, blockBin, epck, E);
    csr_local<<<NB, 256, 0, stream>>>(epck, binBase, rowptr, eidx, N);

    // ---- layer 1: agg6 + matmul -> hA raw; stats1; h16 = bn-relu fp16 ----
    sage1_fused<<<nodeBlocks, 256, 0, stream>>>(rowptr, eidx, x, W1l, b1, W1r, hA, N);
    bn_stats<<<1024, 256, 0, stream>>>(hA, stats, N64);
    bn16<<<cvtBlocks, 256, 0, stream>>>(hA, stats, g1, be1, h16, invN, N64);

    // ---- layer 2 ----
    aggpull16<<<waveNodeBlocks, 256, 0, stream>>>(rowptr, eidx, h16, agg16, N);
    mm64_h16<<<mmBlocks, 256, 0, stream>>>(agg16, h16, W2l, b2, W2r, hB, N);
    bn_stats<<<1024, 256, 0, stream>>>(hB, stats + 128, N64);
    bn16<<<cvtBlocks, 256, 0, stream>>>(hB, stats + 128, g2, be2, h16, invN, N64);

    // ---- layer 3 ----
    aggpull16<<<waveNodeBlocks, 256, 0, stream>>>(rowptr, eidx, h16, agg16, N);
    mm64_h16<<<mmBlocks, 256, 0, stream>>>(agg16, h16, W3l, b3, W3r, hA, N);
    bn_stats<<<1024, 256, 0, stream>>>(hA, stats + 256, N64);

    // ---- fused BN3 + attention pooling + heads ----
    bn_pool<<<PBLK, 256, 0, stream>>>(hA, stats + 256, g3, be3, x, batch,
                                      rawpool, invN, N, chunk);
    heads_kernel<<<64, 64, 0, stream>>>(rawpool, sumexp, lb,
                                        phW1, phb1, phW2, phb2,
                                        trW1, trb1, trW2, trb2, out);
}